// Round 1
// 949.995 us; speedup vs baseline: 8.1998x; 8.1998x over previous
//
#include <hip/hip_runtime.h>

// Problem constants
#define BB 4
#define SS 1024
#define HH 768
#define NH 12
#define DD 64
#define SPAN 256      // BUCKETS
#define TWOSPAN 512
#define NBH (BB * NH)                   // 48
#define TOT (BB * SS * HH)              // 3,145,728
#define POSTOT (TWOSPAN * HH)           // 393,216
#define WTOT (HH * HH)                  // 589,824

typedef unsigned short u16;
typedef __attribute__((ext_vector_type(8))) short bf16x8;   // 8 bf16 (4 VGPRs)
typedef __attribute__((ext_vector_type(4))) float f32x4;    // MFMA 16x16 accumulator

// ---------------------------------------------------------------------------
// Static device storage.  Input mirrors (bf16) + computed tensors.
// All fully rewritten every launch before being read.
// ---------------------------------------------------------------------------
__device__ u16 g_hid[TOT];
__device__ u16 g_rel[POSTOT];
__device__ u16 g_Wq[WTOT];
__device__ u16 g_Wk[WTOT];
__device__ u16 g_Wv[WTOT];
__device__ u16 g_Wo[WTOT];
__device__ u16 g_bq[HH];
__device__ u16 g_bk[HH];
__device__ u16 g_bv[HH];
__device__ u16 g_bo[HH];
__device__ u16 g_lnw[HH];
__device__ u16 g_lnb[HH];

__device__ u16 g_q[TOT];
__device__ u16 g_k[TOT];
__device__ u16 g_v[TOT];
__device__ u16 g_ctx[TOT];
__device__ u16 g_posk[POSTOT];
__device__ u16 g_posq[POSTOT];

__device__ u16   g_vt[NBH * DD * SS];            // V^T per (b,h): [48][64][1024] bf16
__device__ u16   g_pbf[48 * 1024 * 1024];        // probs bf16 for PV MFMA
__device__ float g_scores[48 * 1024 * 1024];     // fp32 scores
__device__ float g_c2p[48 * 1024 * 512];         // c2p_att[bh][s][j]
__device__ float g_p2cT[48 * 512 * 1024];        // p2c_att^T[bh][j][t]  (coalesced gather)
__device__ float g_oproj[TOT];                   // ctx @ Wo^T + bo (fp32)
__device__ int g_relidx[2048];
__device__ int g_isfp32;

__device__ __forceinline__ float b2f(u16 u) {
    union { unsigned int i; float f; } x;
    x.i = ((unsigned int)u) << 16;
    return x.f;
}
// fp32 -> bf16 round-to-nearest-even
__device__ __forceinline__ u16 f2b(float f) {
    union { float f; unsigned int i; } x;
    x.f = f;
    unsigned int r = x.i + 0x7fffu + ((x.i >> 16) & 1u);
    return (u16)(r >> 16);
}

// ---------------------------------------------------------------------------
// Kernel 0: input dtype detection (unchanged, harness-verified).
// ---------------------------------------------------------------------------
__global__ void detect_dtype(const u16* __restrict__ hid) {
    __shared__ int cnt;
    if (threadIdx.x == 0) cnt = 0;
    __syncthreads();
    const u16 u = hid[threadIdx.x * 2];
    const int e = (u >> 7) & 0xFF;
    if (e >= 130) atomicAdd(&cnt, 1);
    __syncthreads();
    if (threadIdx.x == 0) g_isfp32 = (cnt >= 16) ? 1 : 0;
}

__global__ void convert_in(const void* __restrict__ src, u16* __restrict__ dst, int n) {
    const int i = blockIdx.x * blockDim.x + threadIdx.x;
    if (i >= n) return;
    if (g_isfp32) dst[i] = f2b(((const float*)src)[i]);
    else          dst[i] = ((const u16*)src)[i];
}

// ---------------------------------------------------------------------------
// Kernel 1: relative-position bucket index table (unchanged).
// ---------------------------------------------------------------------------
__global__ void build_relidx() {
    int i = blockIdx.x * blockDim.x + threadIdx.x;
    if (i >= 2047) return;
    int delta = i - 1023;
    int ad = delta < 0 ? -delta : delta;
    int bucket;
    if (ad <= 128) {
        bucket = delta;
    } else {
        float num = logf((float)ad / 128.0f);
        double v = (double)num / log(511.0 / 128.0) * 127.0;
        int lp = (int)ceil(v) + 128;
        bucket = (delta > 0) ? lp : -lp;
    }
    int idx = bucket + SPAN;
    idx = idx < 0 ? 0 : (idx > 511 ? 511 : idx);
    g_relidx[i] = idx;
}

// ---------------------------------------------------------------------------
// Generic MFMA NT-GEMM:  C[m,n] = sum_k A[m,k]*B[n,k] (+ bias[n])
// A,B bf16 row-major; C fp32 or bf16.  128x128 tile, 4 waves (2x2 of 64x64).
// Optional (b,h) batching via per-operand strides; batch = blockIdx.z,
// b = z/NH, h = z%NH.
// Fragment layout (16x16x32 bf16): operand lane l reads row (l&15),
// 8 contiguous k at (l>>4)*8; D: col = l&15, row = (l>>4)*4 + reg.
// ---------------------------------------------------------------------------
__global__ __launch_bounds__(256) void mfma_nt_gemm(
    const u16* __restrict__ A, const u16* __restrict__ B, const u16* __restrict__ bias,
    void* __restrict__ C, int lda, int ldb, int ldc, int K, int c_f32,
    unsigned long long aSb, unsigned long long aSh,
    unsigned long long bSb, unsigned long long bSh,
    unsigned long long cSb, unsigned long long cSh)
{
    const int z = blockIdx.z;
    const int bz = z / NH, hz = z % NH;
    A += (size_t)bz * aSb + (size_t)hz * aSh;
    B += (size_t)bz * bSb + (size_t)hz * bSh;
    const size_t coff = (size_t)bz * cSb + (size_t)hz * cSh;

    const int tid = threadIdx.x;
    const int w  = tid >> 6;
    const int l  = tid & 63;
    const int lr = l & 15;
    const int lk = (l >> 4) << 3;
    const int rr = (l >> 4) << 2;
    const int m0 = blockIdx.y * 128 + (w >> 1) * 64;
    const int n0 = blockIdx.x * 128 + (w & 1) * 64;

    f32x4 acc[4][4] = {};
    for (int k0 = 0; k0 < K; k0 += 32) {
        bf16x8 af[4], bfr[4];
        #pragma unroll
        for (int m = 0; m < 4; ++m)
            af[m] = *(const bf16x8*)(A + (size_t)(m0 + m * 16 + lr) * lda + k0 + lk);
        #pragma unroll
        for (int n = 0; n < 4; ++n)
            bfr[n] = *(const bf16x8*)(B + (size_t)(n0 + n * 16 + lr) * ldb + k0 + lk);
        #pragma unroll
        for (int m = 0; m < 4; ++m)
            #pragma unroll
            for (int n = 0; n < 4; ++n)
                acc[m][n] = __builtin_amdgcn_mfma_f32_16x16x32_bf16(af[m], bfr[n], acc[m][n], 0, 0, 0);
    }

    #pragma unroll
    for (int m = 0; m < 4; ++m) {
        #pragma unroll
        for (int n = 0; n < 4; ++n) {
            const int col = n0 + n * 16 + lr;
            const float bv = bias ? b2f(bias[col]) : 0.f;
            #pragma unroll
            for (int r = 0; r < 4; ++r) {
                const int row = m0 + m * 16 + rr + r;
                const float v = acc[m][n][r] + bv;
                if (c_f32) ((float*)C)[coff + (size_t)row * ldc + col] = v;
                else       ((u16*)C)[coff + (size_t)row * ldc + col]  = f2b(v);
            }
        }
    }
}

// ---------------------------------------------------------------------------
// V^T per (b,h): g_vt[bh][d][t] = g_v[(b*SS+t)*HH + h*DD + d].  Coalesced read.
// ---------------------------------------------------------------------------
__global__ void vtrans_kernel() {
    const int i = blockIdx.x * 256 + threadIdx.x;     // 48*64*1024 total
    const int d = i & 63;
    const int t = (i >> 6) & 1023;
    const int z = i >> 16;
    const int b = z / NH, h = z % NH;
    g_vt[((size_t)z * DD + d) * SS + t] = g_v[((size_t)(b * SS + t)) * HH + h * DD + d];
}

// ---------------------------------------------------------------------------
// Scores: scores[s,t] = (QK^T + c2p[s,j] + p2cT[j,t]) * rscale,  j = relidx[s-t].
// 128x128 tile per block, 4 waves (2x2).  K=64 fully in registers.
// The rel-index window for a tile is 255 entries -> LDS.
// ---------------------------------------------------------------------------
__global__ __launch_bounds__(256) void score_kernel()
{
    const int z = blockIdx.z;
    const int b = z / NH, h = z % NH;
    const int s0 = blockIdx.y * 128;
    const int t0 = blockIdx.x * 128;
    const int tid = threadIdx.x;
    const int w  = tid >> 6;
    const int l  = tid & 63;
    const int lr = l & 15;
    const int lk = (l >> 4) << 3;
    const int rr = (l >> 4) << 2;

    __shared__ int rel_lds[256];
    if (tid < 255) rel_lds[tid] = g_relidx[s0 - t0 + 896 + tid];
    __syncthreads();

    const int ws = s0 + (w >> 1) * 64;
    const int wt = t0 + (w & 1) * 64;
    const u16* __restrict__ qb = g_q + (size_t)(b * SS) * HH + h * DD;
    const u16* __restrict__ kb = g_k + (size_t)(b * SS) * HH + h * DD;

    bf16x8 aq[4][2], bk[4][2];
    #pragma unroll
    for (int m = 0; m < 4; ++m)
        #pragma unroll
        for (int kk = 0; kk < 2; ++kk)
            aq[m][kk] = *(const bf16x8*)(qb + (size_t)(ws + m * 16 + lr) * HH + kk * 32 + lk);
    #pragma unroll
    for (int n = 0; n < 4; ++n)
        #pragma unroll
        for (int kk = 0; kk < 2; ++kk)
            bk[n][kk] = *(const bf16x8*)(kb + (size_t)(wt + n * 16 + lr) * HH + kk * 32 + lk);

    f32x4 acc[4][4] = {};
    #pragma unroll
    for (int kk = 0; kk < 2; ++kk)
        #pragma unroll
        for (int m = 0; m < 4; ++m)
            #pragma unroll
            for (int n = 0; n < 4; ++n)
                acc[m][n] = __builtin_amdgcn_mfma_f32_16x16x32_bf16(aq[m][kk], bk[n][kk], acc[m][n], 0, 0, 0);

    const float rscale = 0.07216878364870323f;   // 1/sqrt(192)
    const float* __restrict__ c2pb = g_c2p  + (size_t)z * SS * TWOSPAN;
    const float* __restrict__ p2cb = g_p2cT + (size_t)z * TWOSPAN * SS;
    float* __restrict__ scb = g_scores + (size_t)z * SS * SS;

    #pragma unroll
    for (int m = 0; m < 4; ++m) {
        #pragma unroll
        for (int r = 0; r < 4; ++r) {
            const int s  = ws + m * 16 + rr + r;
            const int sl = s - s0;
            #pragma unroll
            for (int n = 0; n < 4; ++n) {
                const int t  = wt + n * 16 + lr;
                const int tl = t - t0;
                const int j  = rel_lds[sl - tl + 127];
                scb[(size_t)s * SS + t] =
                    (acc[m][n][r] + c2pb[(size_t)s * TWOSPAN + j]
                                  + p2cb[(size_t)j * SS + t]) * rscale;
            }
        }
    }
}

// ---------------------------------------------------------------------------
// Row softmax: read fp32 scores, write probs to d_out (flagged dtype) and a
// bf16 copy for the PV MFMA.  One block (256 thr) per (bh, s).
// ---------------------------------------------------------------------------
__global__ __launch_bounds__(256) void softmax_kernel(void* __restrict__ dout, int has_probs)
{
    const int s = blockIdx.x;
    const int z = blockIdx.y;
    const int tid = threadIdx.x;
    __shared__ float red[4];

    const float* __restrict__ row = g_scores + ((size_t)z * SS + s) * SS;
    float v[4];
    #pragma unroll
    for (int c = 0; c < 4; ++c) v[c] = row[c * 256 + tid];

    float m = fmaxf(fmaxf(v[0], v[1]), fmaxf(v[2], v[3]));
    #pragma unroll
    for (int off = 32; off > 0; off >>= 1) m = fmaxf(m, __shfl_down(m, off));
    if ((tid & 63) == 0) red[tid >> 6] = m;
    __syncthreads();
    if (tid == 0) red[0] = fmaxf(fmaxf(red[0], red[1]), fmaxf(red[2], red[3]));
    __syncthreads();
    const float rowmax = red[0];
    __syncthreads();

    float e[4];
    float ssum = 0.f;
    #pragma unroll
    for (int c = 0; c < 4; ++c) { e[c] = __expf(v[c] - rowmax); ssum += e[c]; }
    #pragma unroll
    for (int off = 32; off > 0; off >>= 1) ssum += __shfl_down(ssum, off);
    if ((tid & 63) == 0) red[tid >> 6] = ssum;
    __syncthreads();
    if (tid == 0) red[0] = red[0] + red[1] + red[2] + red[3];
    __syncthreads();
    const float inv = 1.0f / red[0];

    const int isf = g_isfp32;
    u16* __restrict__ pb = g_pbf + ((size_t)z * SS + s) * SS;
    const size_t pbase = ((size_t)z * SS + s) * SS + (size_t)TOT;
    #pragma unroll
    for (int c = 0; c < 4; ++c) {
        const int t = c * 256 + tid;
        const float p = e[c] * inv;
        pb[t] = f2b(p);
        if (has_probs) {
            if (isf) ((float*)dout)[pbase + t] = p;
            else     ((u16*)dout)[pbase + t]   = f2b(p);
        }
    }
}

// ---------------------------------------------------------------------------
// PV: ctx[s,d] = sum_t P[s,t]*V[t,d] via MFMA.  Block = 128 s-rows x 64 d,
// 4 waves stacked in s (each 32x64).  B-operand from pre-transposed V^T.
// ---------------------------------------------------------------------------
__global__ __launch_bounds__(256) void pv_kernel()
{
    const int z = blockIdx.y;
    const int b = z / NH, h = z % NH;
    const int tid = threadIdx.x;
    const int w  = tid >> 6;
    const int l  = tid & 63;
    const int lr = l & 15;
    const int lk = (l >> 4) << 3;
    const int rr = (l >> 4) << 2;
    const int ws = blockIdx.x * 128 + w * 32;

    const u16* __restrict__ P  = g_pbf + (size_t)z * SS * SS;
    const u16* __restrict__ VT = g_vt  + (size_t)z * DD * SS;

    f32x4 acc[2][4] = {};
    for (int kt = 0; kt < SS; kt += 32) {
        bf16x8 af[2], bfr[4];
        #pragma unroll
        for (int m = 0; m < 2; ++m)
            af[m] = *(const bf16x8*)(P + (size_t)(ws + m * 16 + lr) * SS + kt + lk);
        #pragma unroll
        for (int n = 0; n < 4; ++n)
            bfr[n] = *(const bf16x8*)(VT + (size_t)(n * 16 + lr) * SS + kt + lk);
        #pragma unroll
        for (int m = 0; m < 2; ++m)
            #pragma unroll
            for (int n = 0; n < 4; ++n)
                acc[m][n] = __builtin_amdgcn_mfma_f32_16x16x32_bf16(af[m], bfr[n], acc[m][n], 0, 0, 0);
    }

    #pragma unroll
    for (int m = 0; m < 2; ++m)
        #pragma unroll
        for (int n = 0; n < 4; ++n)
            #pragma unroll
            for (int r = 0; r < 4; ++r) {
                const int s = ws + m * 16 + rr + r;
                const int d = n * 16 + lr;
                g_ctx[(size_t)(b * SS + s) * HH + h * DD + d] = f2b(acc[m][n][r]);
            }
}

// ---------------------------------------------------------------------------
// LN epilogue: out = LN( oproj + hidden ).  One block per token row.
// (oproj = ctx @ Wo^T + bo, fp32, computed by mfma_nt_gemm.)
// ---------------------------------------------------------------------------
__global__ __launch_bounds__(256) void ln_kernel(void* __restrict__ dout)
{
    const int row = blockIdx.x;
    const int tid = threadIdx.x;
    __shared__ float os[HH];
    __shared__ float red[4];

    for (int c = tid; c < HH; c += 256)
        os[c] = g_oproj[(size_t)row * HH + c] + b2f(g_hid[(size_t)row * HH + c]);
    __syncthreads();

    float sum = 0.f;
    for (int c = tid; c < HH; c += 256) sum += os[c];
    #pragma unroll
    for (int off = 32; off > 0; off >>= 1) sum += __shfl_down(sum, off);
    if ((tid & 63) == 0) red[tid >> 6] = sum;
    __syncthreads();
    if (tid == 0) red[0] = red[0] + red[1] + red[2] + red[3];
    __syncthreads();
    const float mu = red[0] * (1.0f / HH);
    __syncthreads();

    float vs = 0.f;
    for (int c = tid; c < HH; c += 256) {
        const float dd0 = os[c] - mu;
        vs += dd0 * dd0;
    }
    #pragma unroll
    for (int off = 32; off > 0; off >>= 1) vs += __shfl_down(vs, off);
    if ((tid & 63) == 0) red[tid >> 6] = vs;
    __syncthreads();
    if (tid == 0) red[0] = red[0] + red[1] + red[2] + red[3];
    __syncthreads();
    const float var = red[0] * (1.0f / HH);
    const float rstd = 1.0f / sqrtf(var + 1e-7f);

    const int isf = g_isfp32;
    for (int c = tid; c < HH; c += 256) {
        const float o = b2f(g_lnw[c]) * (os[c] - mu) * rstd + b2f(g_lnb[c]);
        if (isf) ((float*)dout)[(size_t)row * HH + c] = o;
        else     ((u16*)dout)[(size_t)row * HH + c]   = f2b(o);
    }
}

// ---------------------------------------------------------------------------
extern "C" void kernel_launch(void* const* d_in, const int* in_sizes, int n_in,
                              void* d_out, int out_size, void* d_ws, size_t ws_size,
                              hipStream_t stream) {
    detect_dtype<<<1, 256, 0, stream>>>((const u16*)d_in[0]);

    // Symbol addresses (hipGetSymbolAddress is a pure query, graph-capture safe).
    void* p;
    u16 *p_hid, *p_rel, *p_Wq, *p_bq, *p_Wk, *p_bk, *p_Wv, *p_bv, *p_Wo, *p_bo, *p_lnw, *p_lnb;
    u16 *p_q, *p_k, *p_v, *p_ctx, *p_posk, *p_posq;
    float *p_c2p, *p_p2cT, *p_oproj;
    hipGetSymbolAddress(&p, HIP_SYMBOL(g_hid));  p_hid = (u16*)p;
    hipGetSymbolAddress(&p, HIP_SYMBOL(g_rel));  p_rel = (u16*)p;
    hipGetSymbolAddress(&p, HIP_SYMBOL(g_Wq));   p_Wq  = (u16*)p;
    hipGetSymbolAddress(&p, HIP_SYMBOL(g_bq));   p_bq  = (u16*)p;
    hipGetSymbolAddress(&p, HIP_SYMBOL(g_Wk));   p_Wk  = (u16*)p;
    hipGetSymbolAddress(&p, HIP_SYMBOL(g_bk));   p_bk  = (u16*)p;
    hipGetSymbolAddress(&p, HIP_SYMBOL(g_Wv));   p_Wv  = (u16*)p;
    hipGetSymbolAddress(&p, HIP_SYMBOL(g_bv));   p_bv  = (u16*)p;
    hipGetSymbolAddress(&p, HIP_SYMBOL(g_Wo));   p_Wo  = (u16*)p;
    hipGetSymbolAddress(&p, HIP_SYMBOL(g_bo));   p_bo  = (u16*)p;
    hipGetSymbolAddress(&p, HIP_SYMBOL(g_lnw));  p_lnw = (u16*)p;
    hipGetSymbolAddress(&p, HIP_SYMBOL(g_lnb));  p_lnb = (u16*)p;
    hipGetSymbolAddress(&p, HIP_SYMBOL(g_q));    p_q   = (u16*)p;
    hipGetSymbolAddress(&p, HIP_SYMBOL(g_k));    p_k   = (u16*)p;
    hipGetSymbolAddress(&p, HIP_SYMBOL(g_v));    p_v   = (u16*)p;
    hipGetSymbolAddress(&p, HIP_SYMBOL(g_ctx));  p_ctx = (u16*)p;
    hipGetSymbolAddress(&p, HIP_SYMBOL(g_posk)); p_posk = (u16*)p;
    hipGetSymbolAddress(&p, HIP_SYMBOL(g_posq)); p_posq = (u16*)p;
    hipGetSymbolAddress(&p, HIP_SYMBOL(g_c2p));  p_c2p  = (float*)p;
    hipGetSymbolAddress(&p, HIP_SYMBOL(g_p2cT)); p_p2cT = (float*)p;
    hipGetSymbolAddress(&p, HIP_SYMBOL(g_oproj)); p_oproj = (float*)p;

    // convert all inputs into bf16 mirrors (src order per setup_inputs)
    {
        struct { const void* src; int n; u16* dst; } cv[12] = {
            { d_in[0],  TOT,    p_hid }, { d_in[1],  POSTOT, p_rel },
            { d_in[2],  WTOT,   p_Wq  }, { d_in[3],  HH,     p_bq  },
            { d_in[4],  WTOT,   p_Wk  }, { d_in[5],  HH,     p_bk  },
            { d_in[6],  WTOT,   p_Wv  }, { d_in[7],  HH,     p_bv  },
            { d_in[8],  WTOT,   p_Wo  }, { d_in[9],  HH,     p_bo  },
            { d_in[10], HH,     p_lnw }, { d_in[11], HH,     p_lnb },
        };
        for (int i = 0; i < 12; ++i) {
            const int n = cv[i].n;
            convert_in<<<(n + 255) / 256, 256, 0, stream>>>(cv[i].src, cv[i].dst, n);
        }
    }

    build_relidx<<<8, 256, 0, stream>>>();

    const int M = BB * SS;   // 4096
    const unsigned long long Z = 0ull;

    // Projections: q/k/v = hid @ W^T + b   (bf16 out)
    mfma_nt_gemm<<<dim3(HH / 128, M / 128, 1), 256, 0, stream>>>(
        p_hid, p_Wq, p_bq, p_q, HH, HH, HH, HH, 0, Z, Z, Z, Z, Z, Z);
    mfma_nt_gemm<<<dim3(HH / 128, M / 128, 1), 256, 0, stream>>>(
        p_hid, p_Wk, p_bk, p_k, HH, HH, HH, HH, 0, Z, Z, Z, Z, Z, Z);
    mfma_nt_gemm<<<dim3(HH / 128, M / 128, 1), 256, 0, stream>>>(
        p_hid, p_Wv, p_bv, p_v, HH, HH, HH, HH, 0, Z, Z, Z, Z, Z, Z);
    // pos_k / pos_q = rel_emb @ W^T + b   (bf16 out, M = 512)
    mfma_nt_gemm<<<dim3(HH / 128, TWOSPAN / 128, 1), 256, 0, stream>>>(
        p_rel, p_Wk, p_bk, p_posk, HH, HH, HH, HH, 0, Z, Z, Z, Z, Z, Z);
    mfma_nt_gemm<<<dim3(HH / 128, TWOSPAN / 128, 1), 256, 0, stream>>>(
        p_rel, p_Wq, p_bq, p_posq, HH, HH, HH, HH, 0, Z, Z, Z, Z, Z, Z);

    // c2p_att[bh][s][j] = q . posk   (fp32 out, batched over bh)
    mfma_nt_gemm<<<dim3(TWOSPAN / 128, SS / 128, NBH), 256, 0, stream>>>(
        p_q, p_posk, (const u16*)nullptr, p_c2p, HH, HH, TWOSPAN, DD, 1,
        (unsigned long long)SS * HH, (unsigned long long)DD,
        Z,                           (unsigned long long)DD,
        (unsigned long long)NH * SS * TWOSPAN, (unsigned long long)SS * TWOSPAN);
    // p2c_att^T[bh][j][t] = posq . k  (fp32 out, batched over bh)
    mfma_nt_gemm<<<dim3(SS / 128, TWOSPAN / 128, NBH), 256, 0, stream>>>(
        p_posq, p_k, (const u16*)nullptr, p_p2cT, HH, HH, SS, DD, 1,
        Z,                           (unsigned long long)DD,
        (unsigned long long)SS * HH, (unsigned long long)DD,
        (unsigned long long)NH * TWOSPAN * SS, (unsigned long long)TWOSPAN * SS);

    vtrans_kernel<<<(NBH * DD * SS) / 256, 256, 0, stream>>>();

    score_kernel<<<dim3(SS / 128, SS / 128, NBH), 256, 0, stream>>>();

    const long long need = (long long)TOT + (long long)BB * NH * SS * SS;
    const int has_probs = ((long long)out_size >= need) ? 1 : 0;
    softmax_kernel<<<dim3(SS, NBH), 256, 0, stream>>>(d_out, has_probs);

    pv_kernel<<<dim3(SS / 128, NBH), 256, 0, stream>>>();

    // out-projection: oproj = ctx @ Wo^T + bo  (fp32 out)
    mfma_nt_gemm<<<dim3(HH / 128, M / 128, 1), 256, 0, stream>>>(
        p_ctx, p_Wo, p_bo, p_oproj, HH, HH, HH, HH, 1, Z, Z, Z, Z, Z, Z);

    ln_kernel<<<BB * SS, 256, 0, stream>>>(d_out);
}

// Round 2
// 779.891 us; speedup vs baseline: 9.9883x; 1.2181x over previous
//
#include <hip/hip_runtime.h>

// Problem constants
#define BB 4
#define SS 1024
#define HH 768
#define NH 12
#define DD 64
#define SPAN 256      // BUCKETS
#define TWOSPAN 512
#define NBH (BB * NH)                   // 48
#define TOT (BB * SS * HH)              // 3,145,728
#define POSTOT (TWOSPAN * HH)           // 393,216
#define WTOT (HH * HH)                  // 589,824

typedef unsigned short u16;
typedef __attribute__((ext_vector_type(8))) short bf16x8;   // 8 bf16 (4 VGPRs)
typedef __attribute__((ext_vector_type(4))) float f32x4;    // MFMA 16x16 accumulator

// ---------------------------------------------------------------------------
// Static device storage.  Input mirrors (bf16) + computed tensors.
// All fully rewritten every launch before being read.
// ---------------------------------------------------------------------------
__device__ u16 g_hid[TOT];
__device__ u16 g_rel[POSTOT];
__device__ u16 g_Wq[WTOT];
__device__ u16 g_Wk[WTOT];
__device__ u16 g_Wv[WTOT];
__device__ u16 g_Wo[WTOT];
__device__ u16 g_bq[HH];
__device__ u16 g_bk[HH];
__device__ u16 g_bv[HH];
__device__ u16 g_bo[HH];
__device__ u16 g_lnw[HH];
__device__ u16 g_lnb[HH];

__device__ u16 g_q[TOT];
__device__ u16 g_k[TOT];
__device__ u16 g_v[TOT];
__device__ u16 g_ctx[TOT];
__device__ u16 g_posk[POSTOT];
__device__ u16 g_posq[POSTOT];

__device__ u16   g_vt[NBH * DD * SS];            // V^T per (b,h): [48][64][1024] bf16
__device__ float g_c2p[48 * 1024 * 512];         // c2p_att[bh][s][j]
__device__ float g_p2cT[48 * 512 * 1024];        // p2c_att^T[bh][j][t]  (coalesced gather)
__device__ float g_oproj[TOT];                   // ctx @ Wo^T + bo (fp32)
__device__ int g_relidx[2048];
__device__ int g_isfp32;

__device__ __forceinline__ float b2f(u16 u) {
    union { unsigned int i; float f; } x;
    x.i = ((unsigned int)u) << 16;
    return x.f;
}
// fp32 -> bf16 round-to-nearest-even
__device__ __forceinline__ u16 f2b(float f) {
    union { float f; unsigned int i; } x;
    x.f = f;
    unsigned int r = x.i + 0x7fffu + ((x.i >> 16) & 1u);
    return (u16)(r >> 16);
}

// ---------------------------------------------------------------------------
// Kernel 0: input dtype detection (unchanged, harness-verified).
// ---------------------------------------------------------------------------
__global__ void detect_dtype(const u16* __restrict__ hid) {
    __shared__ int cnt;
    if (threadIdx.x == 0) cnt = 0;
    __syncthreads();
    const u16 u = hid[threadIdx.x * 2];
    const int e = (u >> 7) & 0xFF;
    if (e >= 130) atomicAdd(&cnt, 1);
    __syncthreads();
    if (threadIdx.x == 0) g_isfp32 = (cnt >= 16) ? 1 : 0;
}

__global__ void convert_in(const void* __restrict__ src, u16* __restrict__ dst, int n) {
    const int i = blockIdx.x * blockDim.x + threadIdx.x;
    if (i >= n) return;
    if (g_isfp32) dst[i] = f2b(((const float*)src)[i]);
    else          dst[i] = ((const u16*)src)[i];
}

// ---------------------------------------------------------------------------
// Kernel 1: relative-position bucket index table (unchanged).
// ---------------------------------------------------------------------------
__global__ void build_relidx() {
    int i = blockIdx.x * blockDim.x + threadIdx.x;
    if (i >= 2047) return;
    int delta = i - 1023;
    int ad = delta < 0 ? -delta : delta;
    int bucket;
    if (ad <= 128) {
        bucket = delta;
    } else {
        float num = logf((float)ad / 128.0f);
        double v = (double)num / log(511.0 / 128.0) * 127.0;
        int lp = (int)ceil(v) + 128;
        bucket = (delta > 0) ? lp : -lp;
    }
    int idx = bucket + SPAN;
    idx = idx < 0 ? 0 : (idx > 511 ? 511 : idx);
    g_relidx[i] = idx;
}

// ---------------------------------------------------------------------------
// Generic MFMA NT-GEMM:  C[m,n] = sum_k A[m,k]*B[n,k] (+ bias[n])
// A,B bf16 row-major; C fp32 or bf16.  128x128 tile, 4 waves (2x2 of 64x64).
// ---------------------------------------------------------------------------
__global__ __launch_bounds__(256) void mfma_nt_gemm(
    const u16* __restrict__ A, const u16* __restrict__ B, const u16* __restrict__ bias,
    void* __restrict__ C, int lda, int ldb, int ldc, int K, int c_f32,
    unsigned long long aSb, unsigned long long aSh,
    unsigned long long bSb, unsigned long long bSh,
    unsigned long long cSb, unsigned long long cSh)
{
    const int z = blockIdx.z;
    const int bz = z / NH, hz = z % NH;
    A += (size_t)bz * aSb + (size_t)hz * aSh;
    B += (size_t)bz * bSb + (size_t)hz * bSh;
    const size_t coff = (size_t)bz * cSb + (size_t)hz * cSh;

    const int tid = threadIdx.x;
    const int w  = tid >> 6;
    const int l  = tid & 63;
    const int lr = l & 15;
    const int lk = (l >> 4) << 3;
    const int rr = (l >> 4) << 2;
    const int m0 = blockIdx.y * 128 + (w >> 1) * 64;
    const int n0 = blockIdx.x * 128 + (w & 1) * 64;

    f32x4 acc[4][4] = {};
    for (int k0 = 0; k0 < K; k0 += 32) {
        bf16x8 af[4], bfr[4];
        #pragma unroll
        for (int m = 0; m < 4; ++m)
            af[m] = *(const bf16x8*)(A + (size_t)(m0 + m * 16 + lr) * lda + k0 + lk);
        #pragma unroll
        for (int n = 0; n < 4; ++n)
            bfr[n] = *(const bf16x8*)(B + (size_t)(n0 + n * 16 + lr) * ldb + k0 + lk);
        #pragma unroll
        for (int m = 0; m < 4; ++m)
            #pragma unroll
            for (int n = 0; n < 4; ++n)
                acc[m][n] = __builtin_amdgcn_mfma_f32_16x16x32_bf16(af[m], bfr[n], acc[m][n], 0, 0, 0);
    }

    #pragma unroll
    for (int m = 0; m < 4; ++m) {
        #pragma unroll
        for (int n = 0; n < 4; ++n) {
            const int col = n0 + n * 16 + lr;
            const float bv = bias ? b2f(bias[col]) : 0.f;
            #pragma unroll
            for (int r = 0; r < 4; ++r) {
                const int row = m0 + m * 16 + rr + r;
                const float v = acc[m][n][r] + bv;
                if (c_f32) ((float*)C)[coff + (size_t)row * ldc + col] = v;
                else       ((u16*)C)[coff + (size_t)row * ldc + col]  = f2b(v);
            }
        }
    }
}

// ---------------------------------------------------------------------------
// V^T per (b,h): g_vt[bh][d][t] = g_v[(b*SS+t)*HH + h*DD + d].
// ---------------------------------------------------------------------------
__global__ void vtrans_kernel() {
    const int i = blockIdx.x * 256 + threadIdx.x;     // 48*64*1024 total
    const int d = i & 63;
    const int t = (i >> 6) & 1023;
    const int z = i >> 16;
    const int b = z / NH, h = z % NH;
    g_vt[((size_t)z * DD + d) * SS + t] = g_v[((size_t)(b * SS + t)) * HH + h * DD + d];
}

// ---------------------------------------------------------------------------
// Fused attention: scores (QK^T + c2p + p2c gathers) -> softmax -> probs write
// -> PV, all in one kernel.  One block = one (b,h) x 16 query rows.
// LDS holds the 16x1024 fp32 score/prob rows, XOR-swizzled:
//   index(row, col) = row*1024 + (col ^ ((row&7)<<2))
// so that PV's per-column ds_read_b128 (16 lanes = 16 rows, same col-range)
// spreads across banks (2-way, free) instead of a 16-way conflict.
// 4 waves; wave w owns t in [w*256, (w+1)*256).
// ---------------------------------------------------------------------------
__global__ __launch_bounds__(256) void attn_fused_kernel(void* __restrict__ dout, int has_probs)
{
    const int z  = blockIdx.y;             // bh
    const int b  = z / NH, h = z % NH;
    const int s0 = blockIdx.x * 16;
    const int tid = threadIdx.x;
    const int w   = tid >> 6;
    const int l   = tid & 63;
    const int lr  = l & 15;
    const int lk8 = (l >> 4) << 3;         // 0,8,16,24
    const int rr  = (l >> 4) << 2;         // 0,4,8,12

    __shared__ float sc[16 * 1024];        // exactly 64 KiB

    // ---- phase A: QK^T via MFMA + disentangled-bias gathers -> LDS scores
    const u16* __restrict__ qb = g_q + ((size_t)(b * SS + s0)) * HH + h * DD;
    const u16* __restrict__ kb = g_k + ((size_t)(b * SS)) * HH + h * DD;
    const bf16x8 aq0 = *(const bf16x8*)(qb + (size_t)lr * HH + lk8);
    const bf16x8 aq1 = *(const bf16x8*)(qb + (size_t)lr * HH + 32 + lk8);

    const int t0 = w * 256;
    f32x4 acc[16];
    #pragma unroll
    for (int n = 0; n < 16; ++n) {
        const u16* kp = kb + (size_t)(t0 + n * 16 + lr) * HH;
        const bf16x8 bk0 = *(const bf16x8*)(kp + lk8);
        const bf16x8 bk1 = *(const bf16x8*)(kp + 32 + lk8);
        f32x4 a = {};
        a = __builtin_amdgcn_mfma_f32_16x16x32_bf16(aq0, bk0, a, 0, 0, 0);
        a = __builtin_amdgcn_mfma_f32_16x16x32_bf16(aq1, bk1, a, 0, 0, 0);
        acc[n] = a;
    }

    const float rscale = 0.07216878364870323f;   // 1/sqrt(192)
    const float* __restrict__ c2pb = g_c2p  + (size_t)z * SS * TWOSPAN + (size_t)s0 * TWOSPAN;
    const float* __restrict__ p2cb = g_p2cT + (size_t)z * TWOSPAN * SS;
    #pragma unroll
    for (int n = 0; n < 16; ++n) {
        const int t = t0 + n * 16 + lr;
        #pragma unroll
        for (int r = 0; r < 4; ++r) {
            const int srow = rr + r;
            const int j = g_relidx[s0 + srow - t + 1023];
            const float v = (acc[n][r] + c2pb[srow * TWOSPAN + j]
                                       + p2cb[(size_t)j * SS + t]) * rscale;
            sc[srow * 1024 + (t ^ ((srow & 7) << 2))] = v;
        }
    }
    __syncthreads();

    // ---- phase B: row softmax in LDS (16 threads per row)
    {
        const int row = tid >> 4;
        const int ln  = tid & 15;
        float* rowp = sc + row * 1024;
        const int sw = (row & 7) << 2;
        float mx = -1e30f;
        #pragma unroll
        for (int i = 0; i < 64; ++i) mx = fmaxf(mx, rowp[(ln + i * 16) ^ sw]);
        #pragma unroll
        for (int off = 8; off > 0; off >>= 1) mx = fmaxf(mx, __shfl_xor(mx, off));
        float sum = 0.f;
        #pragma unroll
        for (int i = 0; i < 64; ++i) {
            const int idx = (ln + i * 16) ^ sw;
            const float e = __expf(rowp[idx] - mx);
            rowp[idx] = e;
            sum += e;
        }
        #pragma unroll
        for (int off = 8; off > 0; off >>= 1) sum += __shfl_xor(sum, off);
        const float inv = 1.0f / sum;
        #pragma unroll
        for (int i = 0; i < 64; ++i) rowp[(ln + i * 16) ^ sw] *= inv;
    }
    __syncthreads();

    // ---- probs write (coalesced float4 per row; wave w touches only its own
    //      t-quarter, so no barrier needed before phase C's in-wave reuse)
    if (has_probs) {
        const int isf = g_isfp32;
        #pragma unroll 4
        for (int rw = 0; rw < 16; ++rw) {
            const float4 p4 = *(const float4*)&sc[rw * 1024 + ((tid * 4) ^ ((rw & 7) << 2))];
            const size_t base = (size_t)TOT + ((size_t)z * SS + (s0 + rw)) * SS + tid * 4;
            if (isf) {
                *(float4*)((float*)dout + base) = p4;
            } else {
                ushort4 u4;
                u4.x = f2b(p4.x); u4.y = f2b(p4.y); u4.z = f2b(p4.z); u4.w = f2b(p4.w);
                *(ushort4*)((u16*)dout + base) = u4;
            }
        }
    }

    // ---- phase C: PV.  Wave w accumulates its t-quarter; A from LDS (fp32->bf16),
    //      B from pre-transposed V^T (L2-resident).
    const u16* __restrict__ VT = g_vt + (size_t)z * DD * SS;
    f32x4 cacc[4] = {};
    const int swl = (lr & 7) << 2;
    #pragma unroll
    for (int ks = 0; ks < 8; ++ks) {
        const int kt = t0 + ks * 32;
        const int qidx = (kt + lk8) ^ swl;
        const float4 pa0 = *(const float4*)&sc[lr * 1024 + qidx];
        const float4 pa1 = *(const float4*)&sc[lr * 1024 + (qidx ^ 4)];
        bf16x8 pa;
        pa[0] = (short)f2b(pa0.x); pa[1] = (short)f2b(pa0.y);
        pa[2] = (short)f2b(pa0.z); pa[3] = (short)f2b(pa0.w);
        pa[4] = (short)f2b(pa1.x); pa[5] = (short)f2b(pa1.y);
        pa[6] = (short)f2b(pa1.z); pa[7] = (short)f2b(pa1.w);
        #pragma unroll
        for (int n = 0; n < 4; ++n) {
            const bf16x8 bv = *(const bf16x8*)(VT + (size_t)(n * 16 + lr) * SS + kt + lk8);
            cacc[n] = __builtin_amdgcn_mfma_f32_16x16x32_bf16(pa, bv, cacc[n], 0, 0, 0);
        }
    }
    // partial ctx into (now dead) own P-quarter of LDS: cols [t0, t0+64)
    #pragma unroll
    for (int n = 0; n < 4; ++n)
        #pragma unroll
        for (int r = 0; r < 4; ++r) {
            const int srow = rr + r;
            sc[srow * 1024 + ((t0 + n * 16 + lr) ^ ((srow & 7) << 2))] = cacc[n][r];
        }
    __syncthreads();

    // cross-wave reduce + ctx store
    #pragma unroll
    for (int it = 0; it < 4; ++it) {
        const int idx = it * 256 + tid;
        const int srow = idx >> 6;
        const int d = idx & 63;
        const int sw2 = (srow & 7) << 2;
        const float rsum = sc[srow * 1024 + ((0   + d) ^ sw2)]
                         + sc[srow * 1024 + ((256 + d) ^ sw2)]
                         + sc[srow * 1024 + ((512 + d) ^ sw2)]
                         + sc[srow * 1024 + ((768 + d) ^ sw2)];
        g_ctx[((size_t)(b * SS + s0 + srow)) * HH + h * DD + d] = f2b(rsum);
    }
}

// ---------------------------------------------------------------------------
// LN epilogue: out = LN( oproj + hidden ).  One block per token row.
// ---------------------------------------------------------------------------
__global__ __launch_bounds__(256) void ln_kernel(void* __restrict__ dout)
{
    const int row = blockIdx.x;
    const int tid = threadIdx.x;
    __shared__ float os[HH];
    __shared__ float red[4];

    for (int c = tid; c < HH; c += 256)
        os[c] = g_oproj[(size_t)row * HH + c] + b2f(g_hid[(size_t)row * HH + c]);
    __syncthreads();

    float sum = 0.f;
    for (int c = tid; c < HH; c += 256) sum += os[c];
    #pragma unroll
    for (int off = 32; off > 0; off >>= 1) sum += __shfl_down(sum, off);
    if ((tid & 63) == 0) red[tid >> 6] = sum;
    __syncthreads();
    if (tid == 0) red[0] = red[0] + red[1] + red[2] + red[3];
    __syncthreads();
    const float mu = red[0] * (1.0f / HH);
    __syncthreads();

    float vs = 0.f;
    for (int c = tid; c < HH; c += 256) {
        const float dd0 = os[c] - mu;
        vs += dd0 * dd0;
    }
    #pragma unroll
    for (int off = 32; off > 0; off >>= 1) vs += __shfl_down(vs, off);
    if ((tid & 63) == 0) red[tid >> 6] = vs;
    __syncthreads();
    if (tid == 0) red[0] = red[0] + red[1] + red[2] + red[3];
    __syncthreads();
    const float var = red[0] * (1.0f / HH);
    const float rstd = 1.0f / sqrtf(var + 1e-7f);

    const int isf = g_isfp32;
    for (int c = tid; c < HH; c += 256) {
        const float o = b2f(g_lnw[c]) * (os[c] - mu) * rstd + b2f(g_lnb[c]);
        if (isf) ((float*)dout)[(size_t)row * HH + c] = o;
        else     ((u16*)dout)[(size_t)row * HH + c]   = f2b(o);
    }
}

// ---------------------------------------------------------------------------
extern "C" void kernel_launch(void* const* d_in, const int* in_sizes, int n_in,
                              void* d_out, int out_size, void* d_ws, size_t ws_size,
                              hipStream_t stream) {
    detect_dtype<<<1, 256, 0, stream>>>((const u16*)d_in[0]);

    void* p;
    u16 *p_hid, *p_rel, *p_Wq, *p_bq, *p_Wk, *p_bk, *p_Wv, *p_bv, *p_Wo, *p_bo, *p_lnw, *p_lnb;
    u16 *p_q, *p_k, *p_v, *p_ctx, *p_posk, *p_posq;
    float *p_c2p, *p_p2cT, *p_oproj;
    hipGetSymbolAddress(&p, HIP_SYMBOL(g_hid));  p_hid = (u16*)p;
    hipGetSymbolAddress(&p, HIP_SYMBOL(g_rel));  p_rel = (u16*)p;
    hipGetSymbolAddress(&p, HIP_SYMBOL(g_Wq));   p_Wq  = (u16*)p;
    hipGetSymbolAddress(&p, HIP_SYMBOL(g_bq));   p_bq  = (u16*)p;
    hipGetSymbolAddress(&p, HIP_SYMBOL(g_Wk));   p_Wk  = (u16*)p;
    hipGetSymbolAddress(&p, HIP_SYMBOL(g_bk));   p_bk  = (u16*)p;
    hipGetSymbolAddress(&p, HIP_SYMBOL(g_Wv));   p_Wv  = (u16*)p;
    hipGetSymbolAddress(&p, HIP_SYMBOL(g_bv));   p_bv  = (u16*)p;
    hipGetSymbolAddress(&p, HIP_SYMBOL(g_Wo));   p_Wo  = (u16*)p;
    hipGetSymbolAddress(&p, HIP_SYMBOL(g_bo));   p_bo  = (u16*)p;
    hipGetSymbolAddress(&p, HIP_SYMBOL(g_lnw));  p_lnw = (u16*)p;
    hipGetSymbolAddress(&p, HIP_SYMBOL(g_lnb));  p_lnb = (u16*)p;
    hipGetSymbolAddress(&p, HIP_SYMBOL(g_q));    p_q   = (u16*)p;
    hipGetSymbolAddress(&p, HIP_SYMBOL(g_k));    p_k   = (u16*)p;
    hipGetSymbolAddress(&p, HIP_SYMBOL(g_v));    p_v   = (u16*)p;
    hipGetSymbolAddress(&p, HIP_SYMBOL(g_ctx));  p_ctx = (u16*)p;
    hipGetSymbolAddress(&p, HIP_SYMBOL(g_posk)); p_posk = (u16*)p;
    hipGetSymbolAddress(&p, HIP_SYMBOL(g_posq)); p_posq = (u16*)p;
    hipGetSymbolAddress(&p, HIP_SYMBOL(g_c2p));  p_c2p  = (float*)p;
    hipGetSymbolAddress(&p, HIP_SYMBOL(g_p2cT)); p_p2cT = (float*)p;
    hipGetSymbolAddress(&p, HIP_SYMBOL(g_oproj)); p_oproj = (float*)p;

    {
        struct { const void* src; int n; u16* dst; } cv[12] = {
            { d_in[0],  TOT,    p_hid }, { d_in[1],  POSTOT, p_rel },
            { d_in[2],  WTOT,   p_Wq  }, { d_in[3],  HH,     p_bq  },
            { d_in[4],  WTOT,   p_Wk  }, { d_in[5],  HH,     p_bk  },
            { d_in[6],  WTOT,   p_Wv  }, { d_in[7],  HH,     p_bv  },
            { d_in[8],  WTOT,   p_Wo  }, { d_in[9],  HH,     p_bo  },
            { d_in[10], HH,     p_lnw }, { d_in[11], HH,     p_lnb },
        };
        for (int i = 0; i < 12; ++i) {
            const int n = cv[i].n;
            convert_in<<<(n + 255) / 256, 256, 0, stream>>>(cv[i].src, cv[i].dst, n);
        }
    }

    build_relidx<<<8, 256, 0, stream>>>();

    const int M = BB * SS;   // 4096
    const unsigned long long Z = 0ull;

    // Projections: q/k/v = hid @ W^T + b   (bf16 out)
    mfma_nt_gemm<<<dim3(HH / 128, M / 128, 1), 256, 0, stream>>>(
        p_hid, p_Wq, p_bq, p_q, HH, HH, HH, HH, 0, Z, Z, Z, Z, Z, Z);
    mfma_nt_gemm<<<dim3(HH / 128, M / 128, 1), 256, 0, stream>>>(
        p_hid, p_Wk, p_bk, p_k, HH, HH, HH, HH, 0, Z, Z, Z, Z, Z, Z);
    mfma_nt_gemm<<<dim3(HH / 128, M / 128, 1), 256, 0, stream>>>(
        p_hid, p_Wv, p_bv, p_v, HH, HH, HH, HH, 0, Z, Z, Z, Z, Z, Z);
    // pos_k / pos_q = rel_emb @ W^T + b   (bf16 out, M = 512)
    mfma_nt_gemm<<<dim3(HH / 128, TWOSPAN / 128, 1), 256, 0, stream>>>(
        p_rel, p_Wk, p_bk, p_posk, HH, HH, HH, HH, 0, Z, Z, Z, Z, Z, Z);
    mfma_nt_gemm<<<dim3(HH / 128, TWOSPAN / 128, 1), 256, 0, stream>>>(
        p_rel, p_Wq, p_bq, p_posq, HH, HH, HH, HH, 0, Z, Z, Z, Z, Z, Z);

    // c2p_att[bh][s][j] = q . posk   (fp32 out, batched over bh)
    mfma_nt_gemm<<<dim3(TWOSPAN / 128, SS / 128, NBH), 256, 0, stream>>>(
        p_q, p_posk, (const u16*)nullptr, p_c2p, HH, HH, TWOSPAN, DD, 1,
        (unsigned long long)SS * HH, (unsigned long long)DD,
        Z,                           (unsigned long long)DD,
        (unsigned long long)NH * SS * TWOSPAN, (unsigned long long)SS * TWOSPAN);
    // p2c_att^T[bh][j][t] = posq . k  (fp32 out, batched over bh)
    mfma_nt_gemm<<<dim3(SS / 128, TWOSPAN / 128, NBH), 256, 0, stream>>>(
        p_posq, p_k, (const u16*)nullptr, p_p2cT, HH, HH, SS, DD, 1,
        Z,                           (unsigned long long)DD,
        (unsigned long long)SS * HH, (unsigned long long)DD,
        (unsigned long long)NH * TWOSPAN * SS, (unsigned long long)TWOSPAN * SS);

    vtrans_kernel<<<(NBH * DD * SS) / 256, 256, 0, stream>>>();

    const long long need = (long long)TOT + (long long)BB * NH * SS * SS;
    const int has_probs = ((long long)out_size >= need) ? 1 : 0;
    attn_fused_kernel<<<dim3(SS / 16, NBH), 256, 0, stream>>>(d_out, has_probs);

    // out-projection: oproj = ctx @ Wo^T + bo  (fp32 out)
    mfma_nt_gemm<<<dim3(HH / 128, M / 128, 1), 256, 0, stream>>>(
        p_ctx, p_Wo, p_bo, p_oproj, HH, HH, HH, HH, 1, Z, Z, Z, Z, Z, Z);

    ln_kernel<<<BB * SS, 256, 0, stream>>>(d_out);
}

// Round 3
// 669.163 us; speedup vs baseline: 11.6410x; 1.1655x over previous
//
#include <hip/hip_runtime.h>

// Problem constants
#define BB 4
#define SS 1024
#define HH 768
#define NH 12
#define DD 64
#define SPAN 256      // BUCKETS
#define TWOSPAN 512
#define NBH (BB * NH)                   // 48
#define TOT (BB * SS * HH)              // 3,145,728
#define POSTOT (TWOSPAN * HH)           // 393,216
#define WTOT (HH * HH)                  // 589,824
#define QKVLD 2304                      // ld of fused qkv output [4096][2304]

typedef unsigned short u16;
typedef __attribute__((ext_vector_type(8))) short bf16x8;   // 8 bf16 (4 VGPRs)
typedef __attribute__((ext_vector_type(4))) float f32x4;    // MFMA 16x16 accumulator

// ---------------------------------------------------------------------------
// Static device storage.  Input mirrors (bf16) + computed tensors.
// All fully rewritten every launch before being read.
// ---------------------------------------------------------------------------
__device__ u16 g_hid[TOT];
__device__ u16 g_rel[POSTOT];
__device__ u16 g_W3[3 * WTOT];          // rows 0-767: Wq, 768-1535: Wk, 1536-2303: Wv
__device__ u16 g_b3[3 * HH];            // bq | bk | bv
__device__ u16 g_Wo[WTOT];
__device__ u16 g_bo[HH];
__device__ u16 g_lnw[HH];
__device__ u16 g_lnb[HH];

__device__ u16 g_qkv[(BB * SS) * QKVLD];   // [4096][2304]: q | k | v
__device__ u16 g_posqk[TWOSPAN * 1536];    // [512][1536]: posq | posk
__device__ u16 g_ctx[TOT];

__device__ u16 g_vt[NBH * DD * SS];        // V^T per (b,h): [48][64][1024] bf16
__device__ u16 g_c2p[48 * 1024 * 512];     // c2p_att[bh][s][j]   (bf16)
__device__ u16 g_p2cT[48 * 512 * 1024];    // p2c_att^T[bh][j][t] (bf16)
__device__ float g_oproj[TOT];             // ctx @ Wo^T + bo (fp32)
__device__ int g_relidx[2048];
__device__ int g_isfp32;

__device__ __forceinline__ float b2f(u16 u) {
    union { unsigned int i; float f; } x;
    x.i = ((unsigned int)u) << 16;
    return x.f;
}
// fp32 -> bf16 round-to-nearest-even
__device__ __forceinline__ u16 f2b(float f) {
    union { float f; unsigned int i; } x;
    x.f = f;
    unsigned int r = x.i + 0x7fffu + ((x.i >> 16) & 1u);
    return (u16)(r >> 16);
}

// ---------------------------------------------------------------------------
// Kernel 0: input dtype detection (unchanged, harness-verified).
// ---------------------------------------------------------------------------
__global__ void detect_dtype(const u16* __restrict__ hid) {
    __shared__ int cnt;
    if (threadIdx.x == 0) cnt = 0;
    __syncthreads();
    const u16 u = hid[threadIdx.x * 2];
    const int e = (u >> 7) & 0xFF;
    if (e >= 130) atomicAdd(&cnt, 1);
    __syncthreads();
    if (threadIdx.x == 0) g_isfp32 = (cnt >= 16) ? 1 : 0;
}

// ---------------------------------------------------------------------------
// Kernel 0b: single fused convert of all 12 inputs + relidx table build.
// ---------------------------------------------------------------------------
struct Srcs { const void* p[12]; };
#define NCVT (TOT + POSTOT + 4 * WTOT + 6 * HH + 2047)

__device__ __forceinline__ u16 cvt1(const void* p, long long i, int isf) {
    return isf ? f2b(((const float*)p)[i]) : ((const u16*)p)[i];
}

__global__ void fused_convert(Srcs s) {
    long long r = (long long)blockIdx.x * 256 + threadIdx.x;
    const int isf = g_isfp32;
    if (r < TOT) { g_hid[r] = cvt1(s.p[0], r, isf); return; }  r -= TOT;
    if (r < POSTOT) { g_rel[r] = cvt1(s.p[1], r, isf); return; }  r -= POSTOT;
    if (r < WTOT) { g_W3[r] = cvt1(s.p[2], r, isf); return; }  r -= WTOT;        // Wq
    if (r < WTOT) { g_W3[WTOT + r] = cvt1(s.p[4], r, isf); return; }  r -= WTOT; // Wk
    if (r < WTOT) { g_W3[2 * WTOT + r] = cvt1(s.p[6], r, isf); return; }  r -= WTOT; // Wv
    if (r < WTOT) { g_Wo[r] = cvt1(s.p[8], r, isf); return; }  r -= WTOT;
    if (r < HH) { g_b3[r] = cvt1(s.p[3], r, isf); return; }  r -= HH;            // bq
    if (r < HH) { g_b3[HH + r] = cvt1(s.p[5], r, isf); return; }  r -= HH;       // bk
    if (r < HH) { g_b3[2 * HH + r] = cvt1(s.p[7], r, isf); return; }  r -= HH;   // bv
    if (r < HH) { g_bo[r] = cvt1(s.p[9], r, isf); return; }  r -= HH;
    if (r < HH) { g_lnw[r] = cvt1(s.p[10], r, isf); return; }  r -= HH;
    if (r < HH) { g_lnb[r] = cvt1(s.p[11], r, isf); return; }  r -= HH;
    if (r < 2047) {
        int delta = (int)r - 1023;
        int ad = delta < 0 ? -delta : delta;
        int bucket;
        if (ad <= 128) {
            bucket = delta;
        } else {
            float num = logf((float)ad / 128.0f);
            double v = (double)num / log(511.0 / 128.0) * 127.0;
            int lp = (int)ceil(v) + 128;
            bucket = (delta > 0) ? lp : -lp;
        }
        int idx = bucket + SPAN;
        idx = idx < 0 ? 0 : (idx > 511 ? 511 : idx);
        g_relidx[r] = idx;
    }
}

// ---------------------------------------------------------------------------
// Generic MFMA NT-GEMM:  C[m,n] = sum_k A[m,k]*B[n,k] (+ bias[n])
// A,B bf16 row-major; C fp32 or bf16.  128x128 tile, 4 waves (2x2 of 64x64).
// ---------------------------------------------------------------------------
__global__ __launch_bounds__(256) void mfma_nt_gemm(
    const u16* __restrict__ A, const u16* __restrict__ B, const u16* __restrict__ bias,
    void* __restrict__ C, int lda, int ldb, int ldc, int K, int c_f32,
    unsigned long long aSb, unsigned long long aSh,
    unsigned long long bSb, unsigned long long bSh,
    unsigned long long cSb, unsigned long long cSh)
{
    const int z = blockIdx.z;
    const int bz = z / NH, hz = z % NH;
    A += (size_t)bz * aSb + (size_t)hz * aSh;
    B += (size_t)bz * bSb + (size_t)hz * bSh;
    const size_t coff = (size_t)bz * cSb + (size_t)hz * cSh;

    const int tid = threadIdx.x;
    const int w  = tid >> 6;
    const int l  = tid & 63;
    const int lr = l & 15;
    const int lk = (l >> 4) << 3;
    const int rr = (l >> 4) << 2;
    const int m0 = blockIdx.y * 128 + (w >> 1) * 64;
    const int n0 = blockIdx.x * 128 + (w & 1) * 64;

    f32x4 acc[4][4] = {};
    for (int k0 = 0; k0 < K; k0 += 32) {
        bf16x8 af[4], bfr[4];
        #pragma unroll
        for (int m = 0; m < 4; ++m)
            af[m] = *(const bf16x8*)(A + (size_t)(m0 + m * 16 + lr) * lda + k0 + lk);
        #pragma unroll
        for (int n = 0; n < 4; ++n)
            bfr[n] = *(const bf16x8*)(B + (size_t)(n0 + n * 16 + lr) * ldb + k0 + lk);
        #pragma unroll
        for (int m = 0; m < 4; ++m)
            #pragma unroll
            for (int n = 0; n < 4; ++n)
                acc[m][n] = __builtin_amdgcn_mfma_f32_16x16x32_bf16(af[m], bfr[n], acc[m][n], 0, 0, 0);
    }

    #pragma unroll
    for (int m = 0; m < 4; ++m) {
        #pragma unroll
        for (int n = 0; n < 4; ++n) {
            const int col = n0 + n * 16 + lr;
            const float bv = bias ? b2f(bias[col]) : 0.f;
            #pragma unroll
            for (int r = 0; r < 4; ++r) {
                const int row = m0 + m * 16 + rr + r;
                const float v = acc[m][n][r] + bv;
                if (c_f32) ((float*)C)[coff + (size_t)row * ldc + col] = v;
                else       ((u16*)C)[coff + (size_t)row * ldc + col]  = f2b(v);
            }
        }
    }
}

// ---------------------------------------------------------------------------
// V^T per (b,h): g_vt[bh][d][t] = v[(b*SS+t), h*64+d]  (v = qkv col 1536+).
// ---------------------------------------------------------------------------
__global__ void vtrans_kernel() {
    const int i = blockIdx.x * 256 + threadIdx.x;     // 48*64*1024 total
    const int d = i & 63;
    const int t = (i >> 6) & 1023;
    const int z = i >> 16;
    const int b = z / NH, h = z % NH;
    g_vt[((size_t)z * DD + d) * SS + t] =
        g_qkv[((size_t)(b * SS + t)) * QKVLD + 2 * HH + h * DD + d];
}

// ---------------------------------------------------------------------------
// Fused attention v2: QK^T + gathers -> IN-REGISTER softmax -> probs write ->
// PV, one kernel.  One block = one (b,h) x 16 query rows; 4 waves split t.
//
// LDS: P bf16 [16][1024], chunk-swizzled: byte(row,t) =
//      row*2048 + (((t>>3) ^ (row&7))<<4) + (t&7)*2
// so PV's A-fragment ds_read_b128 (16 lanes = 16 rows, same k-range) is
// conflict-free (rows 0-7 cover all 32 banks, rows 8-15 repeat = free 2-way).
// After PV, the buffer is reused for fp32 ctx partials [4][16][64].
//
// Block id is XCD-swizzled: each XCD owns 6 whole heads, so K/V/c2p/p2cT of a
// head are fetched into one XCD's L2 once instead of 8 times.
// ---------------------------------------------------------------------------
__global__ __launch_bounds__(256, 3) void attn_fused_kernel(void* __restrict__ dout, int has_probs)
{
    const int nblk = blockIdx.x;            // 0..3071
    const int xcd  = nblk & 7;
    const int jj0  = nblk >> 3;             // 0..383
    const int z    = xcd * 6 + (jj0 >> 6);  // bh
    const int s0   = (jj0 & 63) * 16;
    const int b    = z / NH, h = z % NH;
    const int tid  = threadIdx.x;
    const int w    = tid >> 6;
    const int l    = tid & 63;
    const int lr   = l & 15;
    const int hi   = l >> 4;
    const int lk8  = hi << 3;               // 0,8,16,24
    const int rr   = hi << 2;               // 0,4,8,12

    __shared__ __align__(16) char smem[32768];   // P bf16, later ctx partials
    __shared__ int   relw[1040];
    __shared__ float redm[4][16];
    __shared__ float reds[4][16];

    // relidx window for this block: j(srow,t) = relw[srow - t + 1023]
    for (int i = tid; i < 1040; i += 256) relw[i] = g_relidx[s0 + i];

    // ---- phase A: QK^T via MFMA (K=64 in registers)
    const u16* __restrict__ qb = g_qkv + ((size_t)(b * SS + s0)) * QKVLD + h * DD;
    const u16* __restrict__ kb = g_qkv + ((size_t)(b * SS)) * QKVLD + HH + h * DD;
    const bf16x8 aq0 = *(const bf16x8*)(qb + (size_t)lr * QKVLD + lk8);
    const bf16x8 aq1 = *(const bf16x8*)(qb + (size_t)lr * QKVLD + 32 + lk8);

    const int t0 = w * 256;
    f32x4 acc[16];
    #pragma unroll
    for (int nn = 0; nn < 16; ++nn) {
        const u16* kp = kb + (size_t)(t0 + nn * 16 + lr) * QKVLD;
        const bf16x8 bk0 = *(const bf16x8*)(kp + lk8);
        const bf16x8 bk1 = *(const bf16x8*)(kp + 32 + lk8);
        f32x4 a = {};
        a = __builtin_amdgcn_mfma_f32_16x16x32_bf16(aq0, bk0, a, 0, 0, 0);
        a = __builtin_amdgcn_mfma_f32_16x16x32_bf16(aq1, bk1, a, 0, 0, 0);
        acc[nn] = a;
    }
    __syncthreads();   // relw ready

    // ---- disentangled-bias gathers (bf16, L2/XCD-local) + scale
    const float rscale = 0.07216878364870323f;   // 1/sqrt(192)
    const u16* __restrict__ c2pb = g_c2p  + ((size_t)z * SS + s0) * TWOSPAN;
    const u16* __restrict__ p2cb = g_p2cT + (size_t)z * TWOSPAN * SS;
    #pragma unroll
    for (int nn = 0; nn < 16; ++nn) {
        const int t = t0 + nn * 16 + lr;
        #pragma unroll
        for (int r = 0; r < 4; ++r) {
            const int srow = rr + r;
            const int j = relw[srow - t + 1023];
            acc[nn][r] = (acc[nn][r] + b2f(c2pb[srow * TWOSPAN + j])
                                     + b2f(p2cb[(size_t)j * SS + t])) * rscale;
        }
    }

    // ---- in-register softmax: row max (16-lane shfl group + cross-wave LDS)
    float mr[4];
    #pragma unroll
    for (int r = 0; r < 4; ++r) {
        float m = acc[0][r];
        #pragma unroll
        for (int nn = 1; nn < 16; ++nn) m = fmaxf(m, acc[nn][r]);
        #pragma unroll
        for (int off = 1; off < 16; off <<= 1) m = fmaxf(m, __shfl_xor(m, off));
        mr[r] = m;
    }
    if (lr == 0) {
        #pragma unroll
        for (int r = 0; r < 4; ++r) redm[w][rr + r] = mr[r];
    }
    __syncthreads();
    #pragma unroll
    for (int r = 0; r < 4; ++r) {
        const int srow = rr + r;
        mr[r] = fmaxf(fmaxf(redm[0][srow], redm[1][srow]),
                      fmaxf(redm[2][srow], redm[3][srow]));
    }

    // exp + sum
    float sr[4] = {0.f, 0.f, 0.f, 0.f};
    #pragma unroll
    for (int nn = 0; nn < 16; ++nn)
        #pragma unroll
        for (int r = 0; r < 4; ++r) {
            const float e = __expf(acc[nn][r] - mr[r]);
            acc[nn][r] = e;
            sr[r] += e;
        }
    #pragma unroll
    for (int r = 0; r < 4; ++r)
        #pragma unroll
        for (int off = 1; off < 16; off <<= 1) sr[r] += __shfl_xor(sr[r], off);
    if (lr == 0) {
        #pragma unroll
        for (int r = 0; r < 4; ++r) reds[w][rr + r] = sr[r];
    }
    __syncthreads();
    float inv[4];
    #pragma unroll
    for (int r = 0; r < 4; ++r) {
        const int srow = rr + r;
        inv[r] = 1.0f / (reds[0][srow] + reds[1][srow] + reds[2][srow] + reds[3][srow]);
    }

    // ---- P write: LDS bf16 (swizzled) + probs to global (full fp32 precision)
    const int isf = g_isfp32;
    #pragma unroll
    for (int nn = 0; nn < 16; ++nn) {
        const int t = t0 + nn * 16 + lr;
        #pragma unroll
        for (int r = 0; r < 4; ++r) {
            const int srow = rr + r;
            const float pv = acc[nn][r] * inv[r];
            const u16 pb = f2b(pv);
            *(u16*)(smem + (srow * 2048 + ((((t >> 3) ^ (srow & 7)) << 4) | ((t & 7) << 1)))) = pb;
            if (has_probs) {
                const size_t base = (size_t)TOT + ((size_t)z * SS + (s0 + srow)) * SS + t;
                if (isf) ((float*)dout)[base] = pv;
                else     ((u16*)dout)[base]   = pb;
            }
        }
    }
    __syncthreads();

    // ---- PV: A = P from LDS (conflict-free b128), B = V^T (L2-resident)
    const u16* __restrict__ VT = g_vt + (size_t)z * DD * SS;
    f32x4 cacc[4] = {};
    #pragma unroll
    for (int ks = 0; ks < 8; ++ks) {
        const int kt = t0 + ks * 32;
        const int tA = kt + lk8;                      // multiple of 8
        const bf16x8 pa = *(const bf16x8*)(smem + (lr * 2048 + ((((tA >> 3) ^ (lr & 7)) << 4))));
        #pragma unroll
        for (int nn = 0; nn < 4; ++nn) {
            const bf16x8 bv = *(const bf16x8*)(VT + (size_t)(nn * 16 + lr) * SS + kt + lk8);
            cacc[nn] = __builtin_amdgcn_mfma_f32_16x16x32_bf16(pa, bv, cacc[nn], 0, 0, 0);
        }
    }
    __syncthreads();   // all P reads complete before reuse

    // ---- cross-wave ctx reduce via reused LDS (fp32 [4][16][64], d swizzled)
    float* ctxp = (float*)smem;
    #pragma unroll
    for (int nn = 0; nn < 4; ++nn)
        #pragma unroll
        for (int r = 0; r < 4; ++r) {
            const int srow = rr + r;
            const int d = nn * 16 + lr;
            ctxp[w * 1024 + srow * 64 + (d ^ ((srow & 3) << 4))] = cacc[nn][r];
        }
    __syncthreads();

    #pragma unroll
    for (int it = 0; it < 4; ++it) {
        const int idx = it * 256 + tid;
        const int srow = idx >> 6;
        const int d = idx & 63;
        const int dd = d ^ ((srow & 3) << 4);
        const float rsum = ctxp[srow * 64 + dd] + ctxp[1024 + srow * 64 + dd]
                         + ctxp[2048 + srow * 64 + dd] + ctxp[3072 + srow * 64 + dd];
        g_ctx[((size_t)(b * SS + s0 + srow)) * HH + h * DD + d] = f2b(rsum);
    }
}

// ---------------------------------------------------------------------------
// LN epilogue: out = LN( oproj + hidden ).  One block per token row.
// ---------------------------------------------------------------------------
__global__ __launch_bounds__(256) void ln_kernel(void* __restrict__ dout)
{
    const int row = blockIdx.x;
    const int tid = threadIdx.x;
    __shared__ float os[HH];
    __shared__ float red[4];

    for (int c = tid; c < HH; c += 256)
        os[c] = g_oproj[(size_t)row * HH + c] + b2f(g_hid[(size_t)row * HH + c]);
    __syncthreads();

    float sum = 0.f;
    for (int c = tid; c < HH; c += 256) sum += os[c];
    #pragma unroll
    for (int off = 32; off > 0; off >>= 1) sum += __shfl_down(sum, off);
    if ((tid & 63) == 0) red[tid >> 6] = sum;
    __syncthreads();
    if (tid == 0) red[0] = red[0] + red[1] + red[2] + red[3];
    __syncthreads();
    const float mu = red[0] * (1.0f / HH);
    __syncthreads();

    float vs = 0.f;
    for (int c = tid; c < HH; c += 256) {
        const float dd0 = os[c] - mu;
        vs += dd0 * dd0;
    }
    #pragma unroll
    for (int off = 32; off > 0; off >>= 1) vs += __shfl_down(vs, off);
    if ((tid & 63) == 0) red[tid >> 6] = vs;
    __syncthreads();
    if (tid == 0) red[0] = red[0] + red[1] + red[2] + red[3];
    __syncthreads();
    const float var = red[0] * (1.0f / HH);
    const float rstd = 1.0f / sqrtf(var + 1e-7f);

    const int isf = g_isfp32;
    for (int c = tid; c < HH; c += 256) {
        const float o = b2f(g_lnw[c]) * (os[c] - mu) * rstd + b2f(g_lnb[c]);
        if (isf) ((float*)dout)[(size_t)row * HH + c] = o;
        else     ((u16*)dout)[(size_t)row * HH + c]   = f2b(o);
    }
}

// ---------------------------------------------------------------------------
extern "C" void kernel_launch(void* const* d_in, const int* in_sizes, int n_in,
                              void* d_out, int out_size, void* d_ws, size_t ws_size,
                              hipStream_t stream) {
    detect_dtype<<<1, 256, 0, stream>>>((const u16*)d_in[0]);

    // single fused convert (+ relidx build)
    Srcs s;
    for (int i = 0; i < 12; ++i) s.p[i] = d_in[i];
    fused_convert<<<(NCVT + 255) / 256, 256, 0, stream>>>(s);

    // Symbol addresses (pure query, graph-capture safe).
    void* p;
    u16 *p_hid, *p_rel, *p_W3, *p_b3, *p_Wo, *p_bo, *p_qkv, *p_posqk, *p_ctx;
    u16 *p_c2p, *p_p2cT;
    float *p_oproj;
    hipGetSymbolAddress(&p, HIP_SYMBOL(g_hid));   p_hid   = (u16*)p;
    hipGetSymbolAddress(&p, HIP_SYMBOL(g_rel));   p_rel   = (u16*)p;
    hipGetSymbolAddress(&p, HIP_SYMBOL(g_W3));    p_W3    = (u16*)p;
    hipGetSymbolAddress(&p, HIP_SYMBOL(g_b3));    p_b3    = (u16*)p;
    hipGetSymbolAddress(&p, HIP_SYMBOL(g_Wo));    p_Wo    = (u16*)p;
    hipGetSymbolAddress(&p, HIP_SYMBOL(g_bo));    p_bo    = (u16*)p;
    hipGetSymbolAddress(&p, HIP_SYMBOL(g_qkv));   p_qkv   = (u16*)p;
    hipGetSymbolAddress(&p, HIP_SYMBOL(g_posqk)); p_posqk = (u16*)p;
    hipGetSymbolAddress(&p, HIP_SYMBOL(g_ctx));   p_ctx   = (u16*)p;
    hipGetSymbolAddress(&p, HIP_SYMBOL(g_c2p));   p_c2p   = (u16*)p;
    hipGetSymbolAddress(&p, HIP_SYMBOL(g_p2cT));  p_p2cT  = (u16*)p;
    hipGetSymbolAddress(&p, HIP_SYMBOL(g_oproj)); p_oproj = (float*)p;

    const int M = BB * SS;   // 4096
    const unsigned long long Z = 0ull;

    // Fused QKV projection: qkv = hid @ W3^T + b3   (bf16, N=2304)
    mfma_nt_gemm<<<dim3(QKVLD / 128, M / 128, 1), 256, 0, stream>>>(
        p_hid, p_W3, p_b3, p_qkv, HH, HH, QKVLD, HH, 0, Z, Z, Z, Z, Z, Z);
    // Fused posq|posk: rel @ [Wq;Wk]^T + [bq;bk]  (bf16, N=1536, M=512)
    mfma_nt_gemm<<<dim3(1536 / 128, TWOSPAN / 128, 1), 256, 0, stream>>>(
        p_rel, p_W3, p_b3, p_posqk, HH, HH, 1536, HH, 0, Z, Z, Z, Z, Z, Z);

    // c2p_att[bh][s][j] = q . posk   (bf16 out, batched over bh)
    mfma_nt_gemm<<<dim3(TWOSPAN / 128, SS / 128, NBH), 256, 0, stream>>>(
        p_qkv, p_posqk + HH, (const u16*)nullptr, p_c2p, QKVLD, 1536, TWOSPAN, DD, 0,
        (unsigned long long)SS * QKVLD, (unsigned long long)DD,
        Z,                              (unsigned long long)DD,
        (unsigned long long)NH * SS * TWOSPAN, (unsigned long long)SS * TWOSPAN);
    // p2c_att^T[bh][j][t] = posq . k  (bf16 out, batched over bh)
    mfma_nt_gemm<<<dim3(SS / 128, TWOSPAN / 128, NBH), 256, 0, stream>>>(
        p_posqk, p_qkv + HH, (const u16*)nullptr, p_p2cT, 1536, QKVLD, SS, DD, 0,
        Z,                               (unsigned long long)DD,
        (unsigned long long)SS * QKVLD,  (unsigned long long)DD,
        (unsigned long long)NH * TWOSPAN * SS, (unsigned long long)TWOSPAN * SS);

    vtrans_kernel<<<(NBH * DD * SS) / 256, 256, 0, stream>>>();

    const long long need = (long long)TOT + (long long)BB * NH * SS * SS;
    const int has_probs = ((long long)out_size >= need) ? 1 : 0;
    attn_fused_kernel<<<NBH * (SS / 16), 256, 0, stream>>>(d_out, has_probs);

    // out-projection: oproj = ctx @ Wo^T + bo  (fp32 out)
    mfma_nt_gemm<<<dim3(HH / 128, M / 128, 1), 256, 0, stream>>>(
        p_ctx, p_Wo, p_bo, p_oproj, HH, HH, HH, HH, 1, Z, Z, Z, Z, Z, Z);

    ln_kernel<<<BB * SS, 256, 0, stream>>>(d_out);
}

// Round 5
// 623.375 us; speedup vs baseline: 12.4961x; 1.0735x over previous
//
#include <hip/hip_runtime.h>

// Problem constants
#define BB 4
#define SS 1024
#define HH 768
#define NH 12
#define DD 64
#define SPAN 256      // BUCKETS
#define TWOSPAN 512
#define NBH (BB * NH)                   // 48
#define TOT (BB * SS * HH)              // 3,145,728
#define POSTOT (TWOSPAN * HH)           // 393,216
#define WTOT (HH * HH)                  // 589,824
#define QKVLD 2304                      // ld of fused qkv output [4096][2304]

typedef unsigned short u16;
typedef __attribute__((ext_vector_type(8))) short bf16x8;   // 8 bf16 (4 VGPRs)
typedef __attribute__((ext_vector_type(4))) float f32x4;    // MFMA 16x16 accumulator

// ---------------------------------------------------------------------------
// Static device storage.  Input mirrors (bf16) + computed tensors.
// All fully rewritten every launch before being read.
// ---------------------------------------------------------------------------
__device__ u16 g_hid[TOT];
__device__ u16 g_rel[POSTOT];
__device__ u16 g_W3[3 * WTOT];          // rows 0-767: Wq, 768-1535: Wk, 1536-2303: Wv
__device__ u16 g_b3[3 * HH];            // bq | bk | bv
__device__ u16 g_Wo[WTOT];
__device__ u16 g_bo[HH];
__device__ u16 g_lnw[HH];
__device__ u16 g_lnb[HH];

__device__ u16 g_qkv[(BB * SS) * QKVLD];   // [4096][2304]: q | k | v
__device__ u16 g_posqk[TWOSPAN * 1536];    // [512][1536]: posq | posk
__device__ u16 g_ctx[TOT];

__device__ u16 g_vt[NBH * DD * SS];        // V^T per (b,h): [48][64][1024] bf16
__device__ u16 g_c2p[48 * 1024 * 512];     // c2p_att[bh][s][j]   (bf16)
__device__ u16 g_p2cT[48 * 512 * 1024];    // p2c_att^T[bh][j][t] (bf16)
__device__ float g_oproj[TOT];             // ctx @ Wo^T + bo (fp32)
__device__ int g_relidx[2048];
__device__ int g_isfp32;

__device__ __forceinline__ float b2f(u16 u) {
    union { unsigned int i; float f; } x;
    x.i = ((unsigned int)u) << 16;
    return x.f;
}
// fp32 -> bf16 round-to-nearest-even
__device__ __forceinline__ u16 f2b(float f) {
    union { float f; unsigned int i; } x;
    x.f = f;
    unsigned int r = x.i + 0x7fffu + ((x.i >> 16) & 1u);
    return (u16)(r >> 16);
}

// async global->LDS, 16B per lane.  LDS dest is wave-uniform base + lane*16.
// NOTE: C-style casts (clang lowers to addrspacecast); static_cast is rejected.
typedef const __attribute__((address_space(1))) unsigned int gas_uint;
typedef __attribute__((address_space(3))) unsigned int las_uint;
__device__ __forceinline__ void gl2lds16(const u16* gp, u16* lp) {
    __builtin_amdgcn_global_load_lds((gas_uint*)gp, (las_uint*)lp, 16, 0, 0);
}

// ---------------------------------------------------------------------------
// Kernel 0: input dtype detection (unchanged, harness-verified).
// ---------------------------------------------------------------------------
__global__ void detect_dtype(const u16* __restrict__ hid) {
    __shared__ int cnt;
    if (threadIdx.x == 0) cnt = 0;
    __syncthreads();
    const u16 u = hid[threadIdx.x * 2];
    const int e = (u >> 7) & 0xFF;
    if (e >= 130) atomicAdd(&cnt, 1);
    __syncthreads();
    if (threadIdx.x == 0) g_isfp32 = (cnt >= 16) ? 1 : 0;
}

// ---------------------------------------------------------------------------
// Kernel 0b: single fused convert of all 12 inputs + relidx table build.
// ---------------------------------------------------------------------------
struct Srcs { const void* p[12]; };
#define NCVT (TOT + POSTOT + 4 * WTOT + 6 * HH + 2047)

__device__ __forceinline__ u16 cvt1(const void* p, long long i, int isf) {
    return isf ? f2b(((const float*)p)[i]) : ((const u16*)p)[i];
}

__global__ void fused_convert(Srcs s) {
    long long r = (long long)blockIdx.x * 256 + threadIdx.x;
    const int isf = g_isfp32;
    if (r < TOT) { g_hid[r] = cvt1(s.p[0], r, isf); return; }  r -= TOT;
    if (r < POSTOT) { g_rel[r] = cvt1(s.p[1], r, isf); return; }  r -= POSTOT;
    if (r < WTOT) { g_W3[r] = cvt1(s.p[2], r, isf); return; }  r -= WTOT;        // Wq
    if (r < WTOT) { g_W3[WTOT + r] = cvt1(s.p[4], r, isf); return; }  r -= WTOT; // Wk
    if (r < WTOT) { g_W3[2 * WTOT + r] = cvt1(s.p[6], r, isf); return; }  r -= WTOT; // Wv
    if (r < WTOT) { g_Wo[r] = cvt1(s.p[8], r, isf); return; }  r -= WTOT;
    if (r < HH) { g_b3[r] = cvt1(s.p[3], r, isf); return; }  r -= HH;            // bq
    if (r < HH) { g_b3[HH + r] = cvt1(s.p[5], r, isf); return; }  r -= HH;       // bk
    if (r < HH) { g_b3[2 * HH + r] = cvt1(s.p[7], r, isf); return; }  r -= HH;   // bv
    if (r < HH) { g_bo[r] = cvt1(s.p[9], r, isf); return; }  r -= HH;
    if (r < HH) { g_lnw[r] = cvt1(s.p[10], r, isf); return; }  r -= HH;
    if (r < HH) { g_lnb[r] = cvt1(s.p[11], r, isf); return; }  r -= HH;
    if (r < 2047) {
        int delta = (int)r - 1023;
        int ad = delta < 0 ? -delta : delta;
        int bucket;
        if (ad <= 128) {
            bucket = delta;
        } else {
            float num = logf((float)ad / 128.0f);
            double v = (double)num / log(511.0 / 128.0) * 127.0;
            int lp = (int)ceil(v) + 128;
            bucket = (delta > 0) ? lp : -lp;
        }
        int idx = bucket + SPAN;
        idx = idx < 0 ? 0 : (idx > 511 ? 511 : idx);
        g_relidx[r] = idx;
    }
}

// ---------------------------------------------------------------------------
// Generic MFMA NT-GEMM (m97-style LDS-staged):
//   C[m,n] = sum_k A[m,k]*B[n,k] (+ bias[n])
// A,B bf16 row-major; C fp32 or bf16.  128x128 tile, BK=64, 4 waves (2x2).
// Staging: global_load_lds width=16, linear LDS [128][64] bf16 per operand.
// Requirements: lda/ldb multiples of 8 elements; K multiple of 64; M,N
// multiples of 128 (all call sites satisfy these).
// ---------------------------------------------------------------------------
__global__ __launch_bounds__(256) void mfma_nt_gemm(
    const u16* __restrict__ A, const u16* __restrict__ B, const u16* __restrict__ bias,
    void* __restrict__ C, int lda, int ldb, int ldc, int K, int c_f32,
    unsigned long long aSb, unsigned long long aSh,
    unsigned long long bSb, unsigned long long bSh,
    unsigned long long cSb, unsigned long long cSh)
{
    const int z = blockIdx.z;
    const int bz = z / NH, hz = z % NH;
    A += (size_t)bz * aSb + (size_t)hz * aSh;
    B += (size_t)bz * bSb + (size_t)hz * bSh;
    const size_t coff = (size_t)bz * cSb + (size_t)hz * cSh;

    __shared__ u16 As[128 * 64];
    __shared__ u16 Bs[128 * 64];

    const int tid = threadIdx.x;
    const int w  = tid >> 6;
    const int l  = tid & 63;
    const int lr = l & 15;
    const int hi = l >> 4;            // 0..3
    const int rr = hi << 2;
    const int m0 = blockIdx.y * 128;
    const int n0 = blockIdx.x * 128;
    const int wm = (w >> 1) * 64;     // wave row offset within tile
    const int wn = (w & 1) * 64;      // wave col offset
    const int srow = l >> 3;          // 0..7  (staging row within chunk)
    const int scol = (l & 7) * 8;     // 0..56 (staging col, elements)

    f32x4 acc[4][4] = {};
    for (int k0 = 0; k0 < K; k0 += 64) {
        // stage A,B 128x64 tiles: 16 chunks of 1KB each, 4 chunks per wave
        #pragma unroll
        for (int ii = 0; ii < 4; ++ii) {
            const int ch = w * 4 + ii;          // 0..15 (wave-uniform)
            const int r  = ch * 8 + srow;       // 0..127
            gl2lds16(A + (size_t)(m0 + r) * lda + k0 + scol, &As[ch * 512]);
            gl2lds16(B + (size_t)(n0 + r) * ldb + k0 + scol, &Bs[ch * 512]);
        }
        __syncthreads();                        // drains vmcnt + barrier

        #pragma unroll
        for (int kk = 0; kk < 2; ++kk) {
            bf16x8 af[4], bfr[4];
            #pragma unroll
            for (int m = 0; m < 4; ++m)
                af[m] = *(const bf16x8*)&As[(wm + m * 16 + lr) * 64 + kk * 32 + hi * 8];
            #pragma unroll
            for (int n = 0; n < 4; ++n)
                bfr[n] = *(const bf16x8*)&Bs[(wn + n * 16 + lr) * 64 + kk * 32 + hi * 8];
            #pragma unroll
            for (int m = 0; m < 4; ++m)
                #pragma unroll
                for (int n = 0; n < 4; ++n)
                    acc[m][n] = __builtin_amdgcn_mfma_f32_16x16x32_bf16(af[m], bfr[n], acc[m][n], 0, 0, 0);
        }
        __syncthreads();                        // all reads done before restage
    }

    #pragma unroll
    for (int m = 0; m < 4; ++m) {
        #pragma unroll
        for (int n = 0; n < 4; ++n) {
            const int col = n0 + wn + n * 16 + lr;
            const float bv = bias ? b2f(bias[col]) : 0.f;
            #pragma unroll
            for (int r = 0; r < 4; ++r) {
                const int row = m0 + wm + m * 16 + rr + r;
                const float v = acc[m][n][r] + bv;
                if (c_f32) ((float*)C)[coff + (size_t)row * ldc + col] = v;
                else       ((u16*)C)[coff + (size_t)row * ldc + col]  = f2b(v);
            }
        }
    }
}

// ---------------------------------------------------------------------------
// V^T per (b,h): g_vt[bh][d][t] = v[(b*SS+t), h*64+d]  (v = qkv col 1536+).
// ---------------------------------------------------------------------------
__global__ void vtrans_kernel() {
    const int i = blockIdx.x * 256 + threadIdx.x;     // 48*64*1024 total
    const int d = i & 63;
    const int t = (i >> 6) & 1023;
    const int z = i >> 16;
    const int b = z / NH, h = z % NH;
    g_vt[((size_t)z * DD + d) * SS + t] =
        g_qkv[((size_t)(b * SS + t)) * QKVLD + 2 * HH + h * DD + d];
}

// ---------------------------------------------------------------------------
// Fused attention v2: QK^T + gathers -> IN-REGISTER softmax -> probs write ->
// PV, one kernel.  One block = one (b,h) x 16 query rows; 4 waves split t.
// (unchanged from round 2)
// ---------------------------------------------------------------------------
__global__ __launch_bounds__(256, 3) void attn_fused_kernel(void* __restrict__ dout, int has_probs)
{
    const int nblk = blockIdx.x;            // 0..3071
    const int xcd  = nblk & 7;
    const int jj0  = nblk >> 3;             // 0..383
    const int z    = xcd * 6 + (jj0 >> 6);  // bh
    const int s0   = (jj0 & 63) * 16;
    const int b    = z / NH, h = z % NH;
    const int tid  = threadIdx.x;
    const int w    = tid >> 6;
    const int l    = tid & 63;
    const int lr   = l & 15;
    const int hi   = l >> 4;
    const int lk8  = hi << 3;               // 0,8,16,24
    const int rr   = hi << 2;               // 0,4,8,12

    __shared__ __align__(16) char smem[32768];   // P bf16, later ctx partials
    __shared__ int   relw[1040];
    __shared__ float redm[4][16];
    __shared__ float reds[4][16];

    // relidx window for this block: j(srow,t) = relw[srow - t + 1023]
    for (int i = tid; i < 1040; i += 256) relw[i] = g_relidx[s0 + i];

    // ---- phase A: QK^T via MFMA (K=64 in registers)
    const u16* __restrict__ qb = g_qkv + ((size_t)(b * SS + s0)) * QKVLD + h * DD;
    const u16* __restrict__ kb = g_qkv + ((size_t)(b * SS)) * QKVLD + HH + h * DD;
    const bf16x8 aq0 = *(const bf16x8*)(qb + (size_t)lr * QKVLD + lk8);
    const bf16x8 aq1 = *(const bf16x8*)(qb + (size_t)lr * QKVLD + 32 + lk8);

    const int t0 = w * 256;
    f32x4 acc[16];
    #pragma unroll
    for (int nn = 0; nn < 16; ++nn) {
        const u16* kp = kb + (size_t)(t0 + nn * 16 + lr) * QKVLD;
        const bf16x8 bk0 = *(const bf16x8*)(kp + lk8);
        const bf16x8 bk1 = *(const bf16x8*)(kp + 32 + lk8);
        f32x4 a = {};
        a = __builtin_amdgcn_mfma_f32_16x16x32_bf16(aq0, bk0, a, 0, 0, 0);
        a = __builtin_amdgcn_mfma_f32_16x16x32_bf16(aq1, bk1, a, 0, 0, 0);
        acc[nn] = a;
    }
    __syncthreads();   // relw ready

    // ---- disentangled-bias gathers (bf16, L2/XCD-local) + scale
    const float rscale = 0.07216878364870323f;   // 1/sqrt(192)
    const u16* __restrict__ c2pb = g_c2p  + ((size_t)z * SS + s0) * TWOSPAN;
    const u16* __restrict__ p2cb = g_p2cT + (size_t)z * TWOSPAN * SS;
    #pragma unroll
    for (int nn = 0; nn < 16; ++nn) {
        const int t = t0 + nn * 16 + lr;
        #pragma unroll
        for (int r = 0; r < 4; ++r) {
            const int srow = rr + r;
            const int j = relw[srow - t + 1023];
            acc[nn][r] = (acc[nn][r] + b2f(c2pb[srow * TWOSPAN + j])
                                     + b2f(p2cb[(size_t)j * SS + t])) * rscale;
        }
    }

    // ---- in-register softmax: row max (16-lane shfl group + cross-wave LDS)
    float mr[4];
    #pragma unroll
    for (int r = 0; r < 4; ++r) {
        float m = acc[0][r];
        #pragma unroll
        for (int nn = 1; nn < 16; ++nn) m = fmaxf(m, acc[nn][r]);
        #pragma unroll
        for (int off = 1; off < 16; off <<= 1) m = fmaxf(m, __shfl_xor(m, off));
        mr[r] = m;
    }
    if (lr == 0) {
        #pragma unroll
        for (int r = 0; r < 4; ++r) redm[w][rr + r] = mr[r];
    }
    __syncthreads();
    #pragma unroll
    for (int r = 0; r < 4; ++r) {
        const int srow = rr + r;
        mr[r] = fmaxf(fmaxf(redm[0][srow], redm[1][srow]),
                      fmaxf(redm[2][srow], redm[3][srow]));
    }

    // exp + sum
    float sr[4] = {0.f, 0.f, 0.f, 0.f};
    #pragma unroll
    for (int nn = 0; nn < 16; ++nn)
        #pragma unroll
        for (int r = 0; r < 4; ++r) {
            const float e = __expf(acc[nn][r] - mr[r]);
            acc[nn][r] = e;
            sr[r] += e;
        }
    #pragma unroll
    for (int r = 0; r < 4; ++r)
        #pragma unroll
        for (int off = 1; off < 16; off <<= 1) sr[r] += __shfl_xor(sr[r], off);
    if (lr == 0) {
        #pragma unroll
        for (int r = 0; r < 4; ++r) reds[w][rr + r] = sr[r];
    }
    __syncthreads();
    float inv[4];
    #pragma unroll
    for (int r = 0; r < 4; ++r) {
        const int srow = rr + r;
        inv[r] = 1.0f / (reds[0][srow] + reds[1][srow] + reds[2][srow] + reds[3][srow]);
    }

    // ---- P write: LDS bf16 (swizzled) + probs to global (full fp32 precision)
    const int isf = g_isfp32;
    #pragma unroll
    for (int nn = 0; nn < 16; ++nn) {
        const int t = t0 + nn * 16 + lr;
        #pragma unroll
        for (int r = 0; r < 4; ++r) {
            const int srow = rr + r;
            const float pv = acc[nn][r] * inv[r];
            const u16 pb = f2b(pv);
            *(u16*)(smem + (srow * 2048 + ((((t >> 3) ^ (srow & 7)) << 4) | ((t & 7) << 1)))) = pb;
            if (has_probs) {
                const size_t base = (size_t)TOT + ((size_t)z * SS + (s0 + srow)) * SS + t;
                if (isf) ((float*)dout)[base] = pv;
                else     ((u16*)dout)[base]   = pb;
            }
        }
    }
    __syncthreads();

    // ---- PV: A = P from LDS (conflict-free b128), B = V^T (L2-resident)
    const u16* __restrict__ VT = g_vt + (size_t)z * DD * SS;
    f32x4 cacc[4] = {};
    #pragma unroll
    for (int ks = 0; ks < 8; ++ks) {
        const int kt = t0 + ks * 32;
        const int tA = kt + lk8;                      // multiple of 8
        const bf16x8 pa = *(const bf16x8*)(smem + (lr * 2048 + ((((tA >> 3) ^ (lr & 7)) << 4))));
        #pragma unroll
        for (int nn = 0; nn < 4; ++nn) {
            const bf16x8 bv = *(const bf16x8*)(VT + (size_t)(nn * 16 + lr) * SS + kt + lk8);
            cacc[nn] = __builtin_amdgcn_mfma_f32_16x16x32_bf16(pa, bv, cacc[nn], 0, 0, 0);
        }
    }
    __syncthreads();   // all P reads complete before reuse

    // ---- cross-wave ctx reduce via reused LDS (fp32 [4][16][64], d swizzled)
    float* ctxp = (float*)smem;
    #pragma unroll
    for (int nn = 0; nn < 4; ++nn)
        #pragma unroll
        for (int r = 0; r < 4; ++r) {
            const int srow = rr + r;
            const int d = nn * 16 + lr;
            ctxp[w * 1024 + srow * 64 + (d ^ ((srow & 3) << 4))] = cacc[nn][r];
        }
    __syncthreads();

    #pragma unroll
    for (int it = 0; it < 4; ++it) {
        const int idx = it * 256 + tid;
        const int srow = idx >> 6;
        const int d = idx & 63;
        const int dd = d ^ ((srow & 3) << 4);
        const float rsum = ctxp[srow * 64 + dd] + ctxp[1024 + srow * 64 + dd]
                         + ctxp[2048 + srow * 64 + dd] + ctxp[3072 + srow * 64 + dd];
        g_ctx[((size_t)(b * SS + s0 + srow)) * HH + h * DD + d] = f2b(rsum);
    }
}

// ---------------------------------------------------------------------------
// LN epilogue: out = LN( oproj + hidden ).  One block per token row.
// ---------------------------------------------------------------------------
__global__ __launch_bounds__(256) void ln_kernel(void* __restrict__ dout)
{
    const int row = blockIdx.x;
    const int tid = threadIdx.x;
    __shared__ float os[HH];
    __shared__ float red[4];

    for (int c = tid; c < HH; c += 256)
        os[c] = g_oproj[(size_t)row * HH + c] + b2f(g_hid[(size_t)row * HH + c]);
    __syncthreads();

    float sum = 0.f;
    for (int c = tid; c < HH; c += 256) sum += os[c];
    #pragma unroll
    for (int off = 32; off > 0; off >>= 1) sum += __shfl_down(sum, off);
    if ((tid & 63) == 0) red[tid >> 6] = sum;
    __syncthreads();
    if (tid == 0) red[0] = red[0] + red[1] + red[2] + red[3];
    __syncthreads();
    const float mu = red[0] * (1.0f / HH);
    __syncthreads();

    float vs = 0.f;
    for (int c = tid; c < HH; c += 256) {
        const float dd0 = os[c] - mu;
        vs += dd0 * dd0;
    }
    #pragma unroll
    for (int off = 32; off > 0; off >>= 1) vs += __shfl_down(vs, off);
    if ((tid & 63) == 0) red[tid >> 6] = vs;
    __syncthreads();
    if (tid == 0) red[0] = red[0] + red[1] + red[2] + red[3];
    __syncthreads();
    const float var = red[0] * (1.0f / HH);
    const float rstd = 1.0f / sqrtf(var + 1e-7f);

    const int isf = g_isfp32;
    for (int c = tid; c < HH; c += 256) {
        const float o = b2f(g_lnw[c]) * (os[c] - mu) * rstd + b2f(g_lnb[c]);
        if (isf) ((float*)dout)[(size_t)row * HH + c] = o;
        else     ((u16*)dout)[(size_t)row * HH + c]   = f2b(o);
    }
}

// ---------------------------------------------------------------------------
extern "C" void kernel_launch(void* const* d_in, const int* in_sizes, int n_in,
                              void* d_out, int out_size, void* d_ws, size_t ws_size,
                              hipStream_t stream) {
    detect_dtype<<<1, 256, 0, stream>>>((const u16*)d_in[0]);

    // single fused convert (+ relidx build)
    Srcs s;
    for (int i = 0; i < 12; ++i) s.p[i] = d_in[i];
    fused_convert<<<(NCVT + 255) / 256, 256, 0, stream>>>(s);

    // Symbol addresses (pure query, graph-capture safe).
    void* p;
    u16 *p_hid, *p_rel, *p_W3, *p_b3, *p_Wo, *p_bo, *p_qkv, *p_posqk, *p_ctx;
    u16 *p_c2p, *p_p2cT;
    float *p_oproj;
    (void)hipGetSymbolAddress(&p, HIP_SYMBOL(g_hid));   p_hid   = (u16*)p;
    (void)hipGetSymbolAddress(&p, HIP_SYMBOL(g_rel));   p_rel   = (u16*)p;
    (void)hipGetSymbolAddress(&p, HIP_SYMBOL(g_W3));    p_W3    = (u16*)p;
    (void)hipGetSymbolAddress(&p, HIP_SYMBOL(g_b3));    p_b3    = (u16*)p;
    (void)hipGetSymbolAddress(&p, HIP_SYMBOL(g_Wo));    p_Wo    = (u16*)p;
    (void)hipGetSymbolAddress(&p, HIP_SYMBOL(g_bo));    p_bo    = (u16*)p;
    (void)hipGetSymbolAddress(&p, HIP_SYMBOL(g_qkv));   p_qkv   = (u16*)p;
    (void)hipGetSymbolAddress(&p, HIP_SYMBOL(g_posqk)); p_posqk = (u16*)p;
    (void)hipGetSymbolAddress(&p, HIP_SYMBOL(g_ctx));   p_ctx   = (u16*)p;
    (void)hipGetSymbolAddress(&p, HIP_SYMBOL(g_c2p));   p_c2p   = (u16*)p;
    (void)hipGetSymbolAddress(&p, HIP_SYMBOL(g_p2cT));  p_p2cT  = (u16*)p;
    (void)hipGetSymbolAddress(&p, HIP_SYMBOL(g_oproj)); p_oproj = (float*)p;

    const int M = BB * SS;   // 4096
    const unsigned long long Z = 0ull;

    // Fused QKV projection: qkv = hid @ W3^T + b3   (bf16, N=2304)
    mfma_nt_gemm<<<dim3(QKVLD / 128, M / 128, 1), 256, 0, stream>>>(
        p_hid, p_W3, p_b3, p_qkv, HH, HH, QKVLD, HH, 0, Z, Z, Z, Z, Z, Z);
    // Fused posq|posk: rel @ [Wq;Wk]^T + [bq;bk]  (bf16, N=1536, M=512)
    mfma_nt_gemm<<<dim3(1536 / 128, TWOSPAN / 128, 1), 256, 0, stream>>>(
        p_rel, p_W3, p_b3, p_posqk, HH, HH, 1536, HH, 0, Z, Z, Z, Z, Z, Z);

    // c2p_att[bh][s][j] = q . posk   (bf16 out, batched over bh)
    mfma_nt_gemm<<<dim3(TWOSPAN / 128, SS / 128, NBH), 256, 0, stream>>>(
        p_qkv, p_posqk + HH, (const u16*)nullptr, p_c2p, QKVLD, 1536, TWOSPAN, DD, 0,
        (unsigned long long)SS * QKVLD, (unsigned long long)DD,
        Z,                              (unsigned long long)DD,
        (unsigned long long)NH * SS * TWOSPAN, (unsigned long long)SS * TWOSPAN);
    // p2c_att^T[bh][j][t] = posq . k  (bf16 out, batched over bh)
    mfma_nt_gemm<<<dim3(SS / 128, TWOSPAN / 128, NBH), 256, 0, stream>>>(
        p_posqk, p_qkv + HH, (const u16*)nullptr, p_p2cT, 1536, QKVLD, SS, DD, 0,
        Z,                               (unsigned long long)DD,
        (unsigned long long)SS * QKVLD,  (unsigned long long)DD,
        (unsigned long long)NH * TWOSPAN * SS, (unsigned long long)TWOSPAN * SS);

    vtrans_kernel<<<(NBH * DD * SS) / 256, 256, 0, stream>>>();

    const long long need = (long long)TOT + (long long)BB * NH * SS * SS;
    const int has_probs = ((long long)out_size >= need) ? 1 : 0;
    attn_fused_kernel<<<NBH * (SS / 16), 256, 0, stream>>>(d_out, has_probs);

    // out-projection: oproj = ctx @ Wo^T + bo  (fp32 out)
    mfma_nt_gemm<<<dim3(HH / 128, M / 128, 1), 256, 0, stream>>>(
        p_ctx, p_Wo, p_bo, p_oproj, HH, HH, HH, HH, 1, Z, Z, Z, Z, Z, Z);

    ln_kernel<<<BB * SS, 256, 0, stream>>>(d_out);
}

// Round 6
// 611.165 us; speedup vs baseline: 12.7458x; 1.0200x over previous
//
#include <hip/hip_runtime.h>

// Problem constants
#define BB 4
#define SS 1024
#define HH 768
#define NH 12
#define DD 64
#define SPAN 256      // BUCKETS
#define TWOSPAN 512
#define NBH (BB * NH)                   // 48
#define TOT (BB * SS * HH)              // 3,145,728
#define POSTOT (TWOSPAN * HH)           // 393,216
#define WTOT (HH * HH)                  // 589,824
#define QKVLD 2304                      // ld of fused qkv output [4096][2304]

typedef unsigned short u16;
typedef __attribute__((ext_vector_type(8))) short bf16x8;   // 8 bf16 (4 VGPRs)
typedef __attribute__((ext_vector_type(4))) float f32x4;    // MFMA 16x16 accumulator

// ---------------------------------------------------------------------------
// Static device storage (16B-aligned for vector access).
// ---------------------------------------------------------------------------
__device__ __align__(16) u16 g_hid[TOT];
__device__ __align__(16) u16 g_rel[POSTOT];
__device__ __align__(16) u16 g_W3[3 * WTOT];   // Wq | Wk | Wv (row blocks)
__device__ __align__(16) u16 g_b3[3 * HH];     // bq | bk | bv
__device__ __align__(16) u16 g_Wo[WTOT];
__device__ __align__(16) u16 g_bo[HH];
__device__ __align__(16) u16 g_lnw[HH];
__device__ __align__(16) u16 g_lnb[HH];

__device__ __align__(16) u16 g_qkv[(BB * SS) * QKVLD];   // [4096][2304]: q|k|v
__device__ __align__(16) u16 g_posqk[TWOSPAN * 1536];    // [512][1536]: posq|posk
__device__ __align__(16) u16 g_ctx[TOT];

__device__ __align__(16) u16 g_vt[NBH * DD * SS];        // V^T per (b,h)
__device__ __align__(16) u16 g_c2p[48 * 1024 * 512];     // c2p[bh][s][j]   bf16
__device__ __align__(16) u16 g_p2c[48 * 1024 * 512];     // p2c[bh][t][j]   bf16 (t-major!)
__device__ float g_oproj[TOT];                           // ctx @ Wo^T + bo (fp32)
__device__ int g_relidx[2048];
__device__ int g_isfp32;

__device__ __forceinline__ float b2f(u16 u) {
    union { unsigned int i; float f; } x;
    x.i = ((unsigned int)u) << 16;
    return x.f;
}
// fp32 -> bf16 round-to-nearest-even
__device__ __forceinline__ u16 f2b(float f) {
    union { float f; unsigned int i; } x;
    x.f = f;
    unsigned int r = x.i + 0x7fffu + ((x.i >> 16) & 1u);
    return (u16)(r >> 16);
}

// async global->LDS, 16B per lane.  LDS dest is wave-uniform base + lane*16.
typedef const __attribute__((address_space(1))) unsigned int gas_uint;
typedef __attribute__((address_space(3))) unsigned int las_uint;
__device__ __forceinline__ void gl2lds16(const u16* gp, u16* lp) {
    __builtin_amdgcn_global_load_lds((gas_uint*)gp, (las_uint*)lp, 16, 0, 0);
}

// ---------------------------------------------------------------------------
// Kernel 0: input dtype detection (unchanged, harness-verified).
// ---------------------------------------------------------------------------
__global__ void detect_dtype(const u16* __restrict__ hid) {
    __shared__ int cnt;
    if (threadIdx.x == 0) cnt = 0;
    __syncthreads();
    const u16 u = hid[threadIdx.x * 2];
    const int e = (u >> 7) & 0xFF;
    if (e >= 130) atomicAdd(&cnt, 1);
    __syncthreads();
    if (threadIdx.x == 0) g_isfp32 = (cnt >= 16) ? 1 : 0;
}

// ---------------------------------------------------------------------------
// Kernel 0b: single fused convert (8 elems/thread) + relidx table build.
// All segment sizes are multiples of 8.
// ---------------------------------------------------------------------------
struct Srcs { const void* p[12]; };
#define NCVT8 ((TOT + POSTOT + 4 * WTOT + 6 * HH) / 8)

__device__ __forceinline__ void cvt8(const void* sp, long long off, u16* dp, int isf) {
    if (isf) {
        const float* f = (const float*)sp + off;
        const float4 a = *(const float4*)f;
        const float4 b = *(const float4*)(f + 4);
        u16 o[8] = { f2b(a.x), f2b(a.y), f2b(a.z), f2b(a.w),
                     f2b(b.x), f2b(b.y), f2b(b.z), f2b(b.w) };
        *(bf16x8*)(dp + off) = *(const bf16x8*)o;
    } else {
        *(bf16x8*)(dp + off) = *(const bf16x8*)((const u16*)sp + off);
    }
}

__global__ void fused_convert(Srcs s) {
    const long long i = (long long)blockIdx.x * 256 + threadIdx.x;
    const int isf = g_isfp32;
    if (i < NCVT8) {
        long long r = i * 8;
        if (r < TOT) { cvt8(s.p[0], r, g_hid, isf); return; }  r -= TOT;
        if (r < POSTOT) { cvt8(s.p[1], r, g_rel, isf); return; }  r -= POSTOT;
        if (r < WTOT) { cvt8(s.p[2], r, g_W3, isf); return; }  r -= WTOT;
        if (r < WTOT) { cvt8(s.p[4], r, g_W3 + WTOT, isf); return; }  r -= WTOT;
        if (r < WTOT) { cvt8(s.p[6], r, g_W3 + 2 * WTOT, isf); return; }  r -= WTOT;
        if (r < WTOT) { cvt8(s.p[8], r, g_Wo, isf); return; }  r -= WTOT;
        if (r < HH) { cvt8(s.p[3], r, g_b3, isf); return; }  r -= HH;
        if (r < HH) { cvt8(s.p[5], r, g_b3 + HH, isf); return; }  r -= HH;
        if (r < HH) { cvt8(s.p[7], r, g_b3 + 2 * HH, isf); return; }  r -= HH;
        if (r < HH) { cvt8(s.p[9], r, g_bo, isf); return; }  r -= HH;
        if (r < HH) { cvt8(s.p[10], r, g_lnw, isf); return; }  r -= HH;
        cvt8(s.p[11], r, g_lnb, isf); return;
    }
    const long long r = i - NCVT8;
    if (r < 2047) {
        int delta = (int)r - 1023;
        int ad = delta < 0 ? -delta : delta;
        int bucket;
        if (ad <= 128) {
            bucket = delta;
        } else {
            float num = logf((float)ad / 128.0f);
            double v = (double)num / log(511.0 / 128.0) * 127.0;
            int lp = (int)ceil(v) + 128;
            bucket = (delta > 0) ? lp : -lp;
        }
        int idx = bucket + SPAN;
        idx = idx < 0 ? 0 : (idx > 511 ? 511 : idx);
        g_relidx[r] = idx;
    }
}

// ---------------------------------------------------------------------------
// Generic MFMA NT-GEMM (m97-style LDS-staged), unchanged from round 5.
// ---------------------------------------------------------------------------
__global__ __launch_bounds__(256) void mfma_nt_gemm(
    const u16* __restrict__ A, const u16* __restrict__ B, const u16* __restrict__ bias,
    void* __restrict__ C, int lda, int ldb, int ldc, int K, int c_f32,
    unsigned long long aSb, unsigned long long aSh,
    unsigned long long bSb, unsigned long long bSh,
    unsigned long long cSb, unsigned long long cSh)
{
    const int z = blockIdx.z;
    const int bz = z / NH, hz = z % NH;
    A += (size_t)bz * aSb + (size_t)hz * aSh;
    B += (size_t)bz * bSb + (size_t)hz * bSh;
    const size_t coff = (size_t)bz * cSb + (size_t)hz * cSh;

    __shared__ u16 As[128 * 64];
    __shared__ u16 Bs[128 * 64];

    const int tid = threadIdx.x;
    const int w  = tid >> 6;
    const int l  = tid & 63;
    const int lr = l & 15;
    const int hi = l >> 4;            // 0..3
    const int rr = hi << 2;
    const int m0 = blockIdx.y * 128;
    const int n0 = blockIdx.x * 128;
    const int wm = (w >> 1) * 64;
    const int wn = (w & 1) * 64;
    const int srow = l >> 3;          // 0..7
    const int scol = (l & 7) * 8;     // 0..56

    f32x4 acc[4][4] = {};
    for (int k0 = 0; k0 < K; k0 += 64) {
        #pragma unroll
        for (int ii = 0; ii < 4; ++ii) {
            const int ch = w * 4 + ii;          // 0..15 (wave-uniform)
            const int r  = ch * 8 + srow;       // 0..127
            gl2lds16(A + (size_t)(m0 + r) * lda + k0 + scol, &As[ch * 512]);
            gl2lds16(B + (size_t)(n0 + r) * ldb + k0 + scol, &Bs[ch * 512]);
        }
        __syncthreads();

        #pragma unroll
        for (int kk = 0; kk < 2; ++kk) {
            bf16x8 af[4], bfr[4];
            #pragma unroll
            for (int m = 0; m < 4; ++m)
                af[m] = *(const bf16x8*)&As[(wm + m * 16 + lr) * 64 + kk * 32 + hi * 8];
            #pragma unroll
            for (int n = 0; n < 4; ++n)
                bfr[n] = *(const bf16x8*)&Bs[(wn + n * 16 + lr) * 64 + kk * 32 + hi * 8];
            #pragma unroll
            for (int m = 0; m < 4; ++m)
                #pragma unroll
                for (int n = 0; n < 4; ++n)
                    acc[m][n] = __builtin_amdgcn_mfma_f32_16x16x32_bf16(af[m], bfr[n], acc[m][n], 0, 0, 0);
        }
        __syncthreads();
    }

    #pragma unroll
    for (int m = 0; m < 4; ++m) {
        #pragma unroll
        for (int n = 0; n < 4; ++n) {
            const int col = n0 + wn + n * 16 + lr;
            const float bv = bias ? b2f(bias[col]) : 0.f;
            #pragma unroll
            for (int r = 0; r < 4; ++r) {
                const int row = m0 + wm + m * 16 + rr + r;
                const float v = acc[m][n][r] + bv;
                if (c_f32) ((float*)C)[coff + (size_t)row * ldc + col] = v;
                else       ((u16*)C)[coff + (size_t)row * ldc + col]  = f2b(v);
            }
        }
    }
}

// ---------------------------------------------------------------------------
// V^T per (b,h): g_vt[bh][d][t] = v[(b*SS+t), h*64+d]  (v = qkv col 1536+).
// ---------------------------------------------------------------------------
__global__ void vtrans_kernel() {
    const int i = blockIdx.x * 256 + threadIdx.x;     // 48*64*1024 total
    const int d = i & 63;
    const int t = (i >> 6) & 1023;
    const int z = i >> 16;
    const int b = z / NH, h = z % NH;
    g_vt[((size_t)z * DD + d) * SS + t] =
        g_qkv[((size_t)(b * SS + t)) * QKVLD + 2 * HH + h * DD + d];
}

// ---------------------------------------------------------------------------
// Fused attention v3.  One block = one (b,h) x 16 query rows; 4 waves split t.
// Changes vs v2:
//  - c2p rows staged into LDS (overlaying the P buffer; consumed before P write)
//  - p2c read from t-major layout [bh][t][j]: the 4 per-lane gathers (r=0..3,
//    j monotone steps 0/1) share one cache line
//  - probs written from LDS P as 16B chunks (bf16-rounded; err <= 2^-9)
//  - 4 blocks/CU
// ---------------------------------------------------------------------------
__global__ __launch_bounds__(256, 4) void attn_fused_kernel(void* __restrict__ dout, int has_probs)
{
    const int nblk = blockIdx.x;            // 0..3071
    const int xcd  = nblk & 7;
    const int jj0  = nblk >> 3;             // 0..383
    const int z    = xcd * 6 + (jj0 >> 6);  // bh
    const int s0   = (jj0 & 63) * 16;
    const int b    = z / NH, h = z % NH;
    const int tid  = threadIdx.x;
    const int w    = tid >> 6;
    const int l    = tid & 63;
    const int lr   = l & 15;
    const int hi   = l >> 4;
    const int lk8  = hi << 3;               // 0,8,16,24
    const int rr   = hi << 2;               // 0,4,8,12

    __shared__ __align__(16) char smem[32768];   // c2p stage -> P bf16 -> ctx partials
    __shared__ int   relw[1040];
    __shared__ float redm[4][16];
    __shared__ float reds[4][16];

    // relidx window: j(srow,t) = relw[srow - t + 1023]
    for (int i = tid; i < 1040; i += 256) relw[i] = g_relidx[s0 + i];

    // stage the 16 c2p rows into smem (stride 520 u16 to spread banks)
    u16* c2p_lds = (u16*)smem;
    {
        const u16* __restrict__ c2pg = g_c2p + ((size_t)z * SS + s0) * TWOSPAN;
        #pragma unroll
        for (int ii = 0; ii < 4; ++ii) {
            const int row = w * 4 + ii;     // wave-uniform 0..15
            gl2lds16(c2pg + (size_t)row * TWOSPAN + l * 8, &c2p_lds[row * 520]);
        }
    }

    // ---- phase A: QK^T via MFMA (K=64 in registers)
    const u16* __restrict__ qb = g_qkv + ((size_t)(b * SS + s0)) * QKVLD + h * DD;
    const u16* __restrict__ kb = g_qkv + ((size_t)(b * SS)) * QKVLD + HH + h * DD;
    const bf16x8 aq0 = *(const bf16x8*)(qb + (size_t)lr * QKVLD + lk8);
    const bf16x8 aq1 = *(const bf16x8*)(qb + (size_t)lr * QKVLD + 32 + lk8);

    const int t0 = w * 256;
    f32x4 acc[16];
    #pragma unroll
    for (int nn = 0; nn < 16; ++nn) {
        const u16* kp = kb + (size_t)(t0 + nn * 16 + lr) * QKVLD;
        const bf16x8 bk0 = *(const bf16x8*)(kp + lk8);
        const bf16x8 bk1 = *(const bf16x8*)(kp + 32 + lk8);
        f32x4 a = {};
        a = __builtin_amdgcn_mfma_f32_16x16x32_bf16(aq0, bk0, a, 0, 0, 0);
        a = __builtin_amdgcn_mfma_f32_16x16x32_bf16(aq1, bk1, a, 0, 0, 0);
        acc[nn] = a;
    }
    __syncthreads();   // relw + c2p stage ready

    // ---- disentangled-bias gathers + scale
    const float rscale = 0.07216878364870323f;   // 1/sqrt(192)
    const u16* __restrict__ p2cb = g_p2c + (size_t)z * SS * TWOSPAN;   // [t][j]
    #pragma unroll
    for (int nn = 0; nn < 16; ++nn) {
        const int t = t0 + nn * 16 + lr;
        const u16* __restrict__ p2crow = p2cb + (size_t)t * TWOSPAN;
        #pragma unroll
        for (int r = 0; r < 4; ++r) {
            const int srow = rr + r;
            const int j = relw[srow - t + 1023];
            acc[nn][r] = (acc[nn][r] + b2f(c2p_lds[srow * 520 + j])
                                     + b2f(p2crow[j])) * rscale;
        }
    }

    // ---- in-register softmax: row max (16-lane shfl group + cross-wave LDS)
    float mr[4];
    #pragma unroll
    for (int r = 0; r < 4; ++r) {
        float m = acc[0][r];
        #pragma unroll
        for (int nn = 1; nn < 16; ++nn) m = fmaxf(m, acc[nn][r]);
        #pragma unroll
        for (int off = 1; off < 16; off <<= 1) m = fmaxf(m, __shfl_xor(m, off));
        mr[r] = m;
    }
    if (lr == 0) {
        #pragma unroll
        for (int r = 0; r < 4; ++r) redm[w][rr + r] = mr[r];
    }
    __syncthreads();
    #pragma unroll
    for (int r = 0; r < 4; ++r) {
        const int srow = rr + r;
        mr[r] = fmaxf(fmaxf(redm[0][srow], redm[1][srow]),
                      fmaxf(redm[2][srow], redm[3][srow]));
    }

    // exp + sum
    float sr[4] = {0.f, 0.f, 0.f, 0.f};
    #pragma unroll
    for (int nn = 0; nn < 16; ++nn)
        #pragma unroll
        for (int r = 0; r < 4; ++r) {
            const float e = __expf(acc[nn][r] - mr[r]);
            acc[nn][r] = e;
            sr[r] += e;
        }
    #pragma unroll
    for (int r = 0; r < 4; ++r)
        #pragma unroll
        for (int off = 1; off < 16; off <<= 1) sr[r] += __shfl_xor(sr[r], off);
    if (lr == 0) {
        #pragma unroll
        for (int r = 0; r < 4; ++r) reds[w][rr + r] = sr[r];
    }
    __syncthreads();
    float inv[4];
    #pragma unroll
    for (int r = 0; r < 4; ++r) {
        const int srow = rr + r;
        inv[r] = 1.0f / (reds[0][srow] + reds[1][srow] + reds[2][srow] + reds[3][srow]);
    }

    // ---- P -> LDS bf16 (swizzled); overlays the (now dead) c2p stage
    #pragma unroll
    for (int nn = 0; nn < 16; ++nn) {
        const int t = t0 + nn * 16 + lr;
        #pragma unroll
        for (int r = 0; r < 4; ++r) {
            const int srow = rr + r;
            const float pv = acc[nn][r] * inv[r];
            *(u16*)(smem + (srow * 2048 + ((((t >> 3) ^ (srow & 7)) << 4) | ((t & 7) << 1)))) = f2b(pv);
        }
    }
    __syncthreads();

    // ---- probs write from LDS: 16B chunks, coalesced
    const int isf = g_isfp32;
    if (has_probs) {
        const int prow = tid >> 4;          // 0..15
        const int pc0  = tid & 15;
        const int swz  = prow & 7;
        const size_t gbase = (size_t)TOT + ((size_t)z * SS + (s0 + prow)) * SS;
        #pragma unroll
        for (int k = 0; k < 8; ++k) {
            const int tc = pc0 + k * 16;    // logical chunk 0..127
            const bf16x8 pv8 = *(const bf16x8*)(smem + prow * 2048 + ((tc ^ swz) << 4));
            if (isf) {
                float4 f0, f1;
                f0.x = b2f((u16)pv8[0]); f0.y = b2f((u16)pv8[1]);
                f0.z = b2f((u16)pv8[2]); f0.w = b2f((u16)pv8[3]);
                f1.x = b2f((u16)pv8[4]); f1.y = b2f((u16)pv8[5]);
                f1.z = b2f((u16)pv8[6]); f1.w = b2f((u16)pv8[7]);
                *(float4*)((float*)dout + gbase + (size_t)tc * 8)     = f0;
                *(float4*)((float*)dout + gbase + (size_t)tc * 8 + 4) = f1;
            } else {
                *(bf16x8*)((u16*)dout + gbase + (size_t)tc * 8) = pv8;
            }
        }
    }

    // ---- PV: A = P from LDS (conflict-free b128), B = V^T (L2-resident)
    const u16* __restrict__ VT = g_vt + (size_t)z * DD * SS;
    f32x4 cacc[4] = {};
    #pragma unroll
    for (int ks = 0; ks < 8; ++ks) {
        const int kt = t0 + ks * 32;
        const int tA = kt + lk8;                      // multiple of 8
        const bf16x8 pa = *(const bf16x8*)(smem + (lr * 2048 + ((((tA >> 3) ^ (lr & 7)) << 4))));
        #pragma unroll
        for (int nn = 0; nn < 4; ++nn) {
            const bf16x8 bv = *(const bf16x8*)(VT + (size_t)(nn * 16 + lr) * SS + kt + lk8);
            cacc[nn] = __builtin_amdgcn_mfma_f32_16x16x32_bf16(pa, bv, cacc[nn], 0, 0, 0);
        }
    }
    __syncthreads();   // all P reads complete before reuse

    // ---- cross-wave ctx reduce via reused LDS (fp32 [4][16][64], d swizzled)
    float* ctxp = (float*)smem;
    #pragma unroll
    for (int nn = 0; nn < 4; ++nn)
        #pragma unroll
        for (int r = 0; r < 4; ++r) {
            const int srow = rr + r;
            const int d = nn * 16 + lr;
            ctxp[w * 1024 + srow * 64 + (d ^ ((srow & 3) << 4))] = cacc[nn][r];
        }
    __syncthreads();

    #pragma unroll
    for (int it = 0; it < 4; ++it) {
        const int idx = it * 256 + tid;
        const int srow = idx >> 6;
        const int d = idx & 63;
        const int dd = d ^ ((srow & 3) << 4);
        const float rsum = ctxp[srow * 64 + dd] + ctxp[1024 + srow * 64 + dd]
                         + ctxp[2048 + srow * 64 + dd] + ctxp[3072 + srow * 64 + dd];
        g_ctx[((size_t)(b * SS + s0 + srow)) * HH + h * DD + d] = f2b(rsum);
    }
}

// ---------------------------------------------------------------------------
// LN epilogue: out = LN( oproj + hidden ).  One block per token row.
// ---------------------------------------------------------------------------
__global__ __launch_bounds__(256) void ln_kernel(void* __restrict__ dout)
{
    const int row = blockIdx.x;
    const int tid = threadIdx.x;
    __shared__ float os[HH];
    __shared__ float red[4];

    for (int c = tid; c < HH; c += 256)
        os[c] = g_oproj[(size_t)row * HH + c] + b2f(g_hid[(size_t)row * HH + c]);
    __syncthreads();

    float sum = 0.f;
    for (int c = tid; c < HH; c += 256) sum += os[c];
    #pragma unroll
    for (int off = 32; off > 0; off >>= 1) sum += __shfl_down(sum, off);
    if ((tid & 63) == 0) red[tid >> 6] = sum;
    __syncthreads();
    if (tid == 0) red[0] = red[0] + red[1] + red[2] + red[3];
    __syncthreads();
    const float mu = red[0] * (1.0f / HH);
    __syncthreads();

    float vs = 0.f;
    for (int c = tid; c < HH; c += 256) {
        const float dd0 = os[c] - mu;
        vs += dd0 * dd0;
    }
    #pragma unroll
    for (int off = 32; off > 0; off >>= 1) vs += __shfl_down(vs, off);
    if ((tid & 63) == 0) red[tid >> 6] = vs;
    __syncthreads();
    if (tid == 0) red[0] = red[0] + red[1] + red[2] + red[3];
    __syncthreads();
    const float var = red[0] * (1.0f / HH);
    const float rstd = 1.0f / sqrtf(var + 1e-7f);

    const int isf = g_isfp32;
    for (int c = tid; c < HH; c += 256) {
        const float o = b2f(g_lnw[c]) * (os[c] - mu) * rstd + b2f(g_lnb[c]);
        if (isf) ((float*)dout)[(size_t)row * HH + c] = o;
        else     ((u16*)dout)[(size_t)row * HH + c]   = f2b(o);
    }
}

// ---------------------------------------------------------------------------
extern "C" void kernel_launch(void* const* d_in, const int* in_sizes, int n_in,
                              void* d_out, int out_size, void* d_ws, size_t ws_size,
                              hipStream_t stream) {
    detect_dtype<<<1, 256, 0, stream>>>((const u16*)d_in[0]);

    // single fused convert (+ relidx build)
    Srcs s;
    for (int i = 0; i < 12; ++i) s.p[i] = d_in[i];
    fused_convert<<<(int)((NCVT8 + 2047 + 255) / 256), 256, 0, stream>>>(s);

    // Symbol addresses (pure query, graph-capture safe).
    void* p;
    u16 *p_hid, *p_rel, *p_W3, *p_b3, *p_Wo, *p_bo, *p_qkv, *p_posqk, *p_ctx;
    u16 *p_c2p, *p_p2c;
    float *p_oproj;
    (void)hipGetSymbolAddress(&p, HIP_SYMBOL(g_hid));   p_hid   = (u16*)p;
    (void)hipGetSymbolAddress(&p, HIP_SYMBOL(g_rel));   p_rel   = (u16*)p;
    (void)hipGetSymbolAddress(&p, HIP_SYMBOL(g_W3));    p_W3    = (u16*)p;
    (void)hipGetSymbolAddress(&p, HIP_SYMBOL(g_b3));    p_b3    = (u16*)p;
    (void)hipGetSymbolAddress(&p, HIP_SYMBOL(g_Wo));    p_Wo    = (u16*)p;
    (void)hipGetSymbolAddress(&p, HIP_SYMBOL(g_bo));    p_bo    = (u16*)p;
    (void)hipGetSymbolAddress(&p, HIP_SYMBOL(g_qkv));   p_qkv   = (u16*)p;
    (void)hipGetSymbolAddress(&p, HIP_SYMBOL(g_posqk)); p_posqk = (u16*)p;
    (void)hipGetSymbolAddress(&p, HIP_SYMBOL(g_ctx));   p_ctx   = (u16*)p;
    (void)hipGetSymbolAddress(&p, HIP_SYMBOL(g_c2p));   p_c2p   = (u16*)p;
    (void)hipGetSymbolAddress(&p, HIP_SYMBOL(g_p2c));   p_p2c   = (u16*)p;
    (void)hipGetSymbolAddress(&p, HIP_SYMBOL(g_oproj)); p_oproj = (float*)p;

    const int M = BB * SS;   // 4096
    const unsigned long long Z = 0ull;

    // Fused QKV projection: qkv = hid @ W3^T + b3   (bf16, N=2304)
    mfma_nt_gemm<<<dim3(QKVLD / 128, M / 128, 1), 256, 0, stream>>>(
        p_hid, p_W3, p_b3, p_qkv, HH, HH, QKVLD, HH, 0, Z, Z, Z, Z, Z, Z);
    // Fused posq|posk: rel @ [Wq;Wk]^T + [bq;bk]  (bf16, N=1536, M=512)
    mfma_nt_gemm<<<dim3(1536 / 128, TWOSPAN / 128, 1), 256, 0, stream>>>(
        p_rel, p_W3, p_b3, p_posqk, HH, HH, 1536, HH, 0, Z, Z, Z, Z, Z, Z);

    // c2p[bh][s][j] = q . posk   (bf16 out, batched over bh)
    mfma_nt_gemm<<<dim3(TWOSPAN / 128, SS / 128, NBH), 256, 0, stream>>>(
        p_qkv, p_posqk + HH, (const u16*)nullptr, p_c2p, QKVLD, 1536, TWOSPAN, DD, 0,
        (unsigned long long)SS * QKVLD, (unsigned long long)DD,
        Z,                              (unsigned long long)DD,
        (unsigned long long)NH * SS * TWOSPAN, (unsigned long long)SS * TWOSPAN);
    // p2c[bh][t][j] = k . posq   (bf16 out, t-major, batched over bh)
    mfma_nt_gemm<<<dim3(TWOSPAN / 128, SS / 128, NBH), 256, 0, stream>>>(
        p_qkv + HH, p_posqk, (const u16*)nullptr, p_p2c, QKVLD, 1536, TWOSPAN, DD, 0,
        (unsigned long long)SS * QKVLD, (unsigned long long)DD,
        Z,                              (unsigned long long)DD,
        (unsigned long long)NH * SS * TWOSPAN, (unsigned long long)SS * TWOSPAN);

    vtrans_kernel<<<(NBH * DD * SS) / 256, 256, 0, stream>>>();

    const long long need = (long long)TOT + (long long)BB * NH * SS * SS;
    const int has_probs = ((long long)out_size >= need) ? 1 : 0;
    attn_fused_kernel<<<NBH * (SS / 16), 256, 0, stream>>>(d_out, has_probs);

    // out-projection: oproj = ctx @ Wo^T + bo  (fp32 out)
    mfma_nt_gemm<<<dim3(HH / 128, M / 128, 1), 256, 0, stream>>>(
        p_ctx, p_Wo, p_bo, p_oproj, HH, HH, HH, HH, 1, Z, Z, Z, Z, Z, Z);

    ln_kernel<<<BB * SS, 256, 0, stream>>>(d_out);
}